// Round 1
// 794.951 us; speedup vs baseline: 1.1009x; 1.1009x over previous
//
#include <hip/hip_runtime.h>
#include <hip/hip_bf16.h>

typedef __attribute__((ext_vector_type(8))) short short8;
typedef __attribute__((ext_vector_type(4))) float f32x4;

// fp32 -> bf16 RNE
static __device__ __forceinline__ unsigned short f2bf(float f) {
    unsigned int x = __float_as_uint(f);
    x += 0x7fffu + ((x >> 16) & 1u);
    return (unsigned short)(x >> 16);
}

// async global->LDS, 16B per lane. LDS dest = wave-uniform base + lane*16.
static __device__ __forceinline__ void gld_lds16(const unsigned short* g, unsigned short* l) {
    __builtin_amdgcn_global_load_lds((const __attribute__((address_space(1))) void*)g,
                                     (__attribute__((address_space(3))) void*)l, 16, 0, 0);
}

// ---------------------------------------------------------------- converts
__global__ __launch_bounds__(256) void cvt_x_kernel(const float* __restrict__ in,
                                                    unsigned short* __restrict__ outb,
                                                    int n4) {
    int i = blockIdx.x * 256 + threadIdx.x;
    if (i < n4) {
        f32x4 v = *(const f32x4*)(in + (size_t)i * 4);
        ushort4 o;
        o.x = f2bf(v[0]); o.y = f2bf(v[1]); o.z = f2bf(v[2]); o.w = f2bf(v[3]);
        *(ushort4*)(outb + (size_t)i * 4) = o;
    }
}

// W [1024 x 3072] fp32  ->  WT [3072 x 1024] bf16   (tiled LDS transpose)
__global__ __launch_bounds__(256) void cvt_wt_kernel(const float* __restrict__ W,
                                                     unsigned short* __restrict__ WT) {
    __shared__ float t[64][65];
    const int n0 = blockIdx.x * 64;   // 48
    const int k0 = blockIdx.y * 64;   // 16
    const int tid = threadIdx.x;
#pragma unroll
    for (int i = 0; i < 16; ++i) {
        int lin = tid + i * 256;
        int rr = lin >> 6, cc = lin & 63;
        t[rr][cc] = W[(size_t)(k0 + rr) * 3072 + n0 + cc];
    }
    __syncthreads();
#pragma unroll
    for (int i = 0; i < 16; ++i) {
        int lin = tid + i * 256;
        int nn = lin >> 6, kk = lin & 63;
        WT[(size_t)(n0 + nn) * 1024 + k0 + kk] = f2bf(t[kk][nn]);
    }
}

// ---------------------------------------------------------------- GEMM
// C[4096,3072] = A[4096,1024] @ W[1024,3072], operands [rows,K] bf16.
// m97 structure: global_load_lds width=16 into LINEAR [128][64] LDS tiles
// (wave-uniform LDS base + lane*16B; per-lane global source). 2-phase loop.
// Epilogue: stage C tile in LDS (reusing As/Bs), COALESCED 16B stores to
// k/q ([B,H,S,64]) or vT ([B,H,64,S]; tile staged transposed in LDS).
__global__ __launch_bounds__(256) void gemm_kqv_kernel(
    const unsigned short* __restrict__ A,   // xb  [4096,1024]
    const unsigned short* __restrict__ BT,  // WTb [3072,1024]
    unsigned short* __restrict__ qb,
    unsigned short* __restrict__ kb,
    unsigned short* __restrict__ vtb) {
    __shared__ __attribute__((aligned(16))) unsigned short smem[2 * 128 * 72];  // 36864 B
    unsigned short (*As)[64] = (unsigned short(*)[64])smem;             // 16 KB
    unsigned short (*Bs)[64] = (unsigned short(*)[64])(smem + 128 * 64);
    const int tid = threadIdx.x;
    const int w = tid >> 6, lane = tid & 63;
    const int quad = lane >> 4, cl = lane & 15;
    const int m0 = blockIdx.y * 128, n0 = blockIdx.x * 128;
    const int wm = (w >> 1) * 64, wn = (w & 1) * 64;

    // staging: wave w covers rows [w*32, w*32+32) of BOTH tiles, 8 rows/instr.
    // lane -> row +lane/8, ushort col (lane&7)*8  (matches lane*16B LDS walk)
    const unsigned short* Ap = A + (size_t)(m0 + w * 32 + (lane >> 3)) * 1024 + (lane & 7) * 8;
    const unsigned short* Bp = BT + (size_t)(n0 + w * 32 + (lane >> 3)) * 1024 + (lane & 7) * 8;

    f32x4 acc[4][4] = {};

    for (int kk = 0; kk < 1024; kk += 64) {
#pragma unroll
        for (int i = 0; i < 4; ++i) {
            gld_lds16(Ap + kk + (size_t)i * 8 * 1024, &As[w * 32 + i * 8][0]);
            gld_lds16(Bp + kk + (size_t)i * 8 * 1024, &Bs[w * 32 + i * 8][0]);
        }
        __syncthreads();   // drains vmcnt -> LDS tiles complete
#pragma unroll
        for (int kc = 0; kc < 2; ++kc) {
            short8 af[4], bfr[4];
#pragma unroll
            for (int i = 0; i < 4; ++i) {
                af[i] = *(const short8*)&As[wm + i * 16 + cl][kc * 32 + quad * 8];
                bfr[i] = *(const short8*)&Bs[wn + i * 16 + cl][kc * 32 + quad * 8];
            }
#pragma unroll
            for (int im = 0; im < 4; ++im)
#pragma unroll
                for (int in = 0; in < 4; ++in)
                    acc[im][in] = __builtin_amdgcn_mfma_f32_16x16x32_bf16(
                        af[im], bfr[in], acc[im][in], 0, 0, 0);
        }
        __syncthreads();
    }
    // k-loop ended with __syncthreads(): safe to reuse smem as C-tile staging.
    unsigned short (*Cs)[130] = (unsigned short(*)[130])smem;  // 33280 B <= 36864 B

    const int chunk = n0 >> 10;           // 0:k 1:q 2:v (jnp.split order)
    const int d0 = n0 & 1023;
    const int b = m0 >> 11;               // tile never crosses batch boundary
    const int s_base = m0 & 2047;

    if (chunk == 2) {
        // stage TRANSPOSED: Cs[d-idx][s-idx]
#pragma unroll
        for (int im = 0; im < 4; ++im)
#pragma unroll
            for (int in = 0; in < 4; ++in)
#pragma unroll
                for (int rg = 0; rg < 4; ++rg)
                    Cs[wn + in * 16 + cl][wm + im * 16 + quad * 4 + rg] =
                        f2bf(acc[im][in][rg]);
        __syncthreads();
#pragma unroll
        for (int it = 0; it < 8; ++it) {
            int l = it * 2048 + tid * 8;
            int c = l >> 7;               // d-index 0..127
            int r = l & 127;              // s-offset (multiple of 8)
            int d = d0 + c, hh = d >> 6, dd = d & 63;
            size_t dst = ((size_t)(b * 16 + hh) * 64 + dd) * 2048 + s_base + r;
            *(uint4*)(vtb + dst) = *(const uint4*)&Cs[c][r];
        }
    } else {
#pragma unroll
        for (int im = 0; im < 4; ++im)
#pragma unroll
            for (int in = 0; in < 4; ++in)
#pragma unroll
                for (int rg = 0; rg < 4; ++rg)
                    Cs[wm + im * 16 + quad * 4 + rg][wn + in * 16 + cl] =
                        f2bf(acc[im][in][rg]);
        __syncthreads();
        unsigned short* outp = (chunk == 0) ? kb : qb;
#pragma unroll
        for (int it = 0; it < 8; ++it) {
            int l = it * 2048 + tid * 8;
            int r = l >> 7;               // s-offset
            int c = l & 127;              // d-index (multiple of 8)
            int d = d0 + c, hh = d >> 6, dd = d & 63;
            size_t dst = ((size_t)(b * 16 + hh) * 2048 + s_base + r) * 64 + dd;
            *(uint4*)(outp + dst) = *(const uint4*)&Cs[r][c];
        }
    }
}

// ---------------------------------------------------------------- fused attention
// grid: (64, h=16, b=2); block 128 = 2 waves x 16 q-rows (32-row q-tile).
// Both waves of a block have IDENTICAL tile count (jtmax = t32>>1).
// t32 swizzled by 37x+11hb so consecutive block ids (-> same CU) carry
// well-spread work; all 2048 blocks resident (8 blocks/CU = 16 waves/CU).
// __launch_bounds__(128,4): VGPR cap 128 so the K/V register pipeline
// actually materializes (old build: 68 VGPR => compiler sank all loads).
__global__ __launch_bounds__(128, 4) void attn_kernel(
    const unsigned short* __restrict__ qb,   // [B,H,S,64]
    const unsigned short* __restrict__ kb,   // [B,H,S,64]
    const unsigned short* __restrict__ vtb,  // [B,H,64,S]
    float* __restrict__ out_,                // [B,S,1024]
    float* __restrict__ attn) {              // [B,H,S,S]
    const int h = blockIdx.y;
    const int b = blockIdx.z;
    const int bh = b * 16 + h;
    const int t32 = (37 * (int)blockIdx.x + 11 * bh) & 63;  // 32-row tile idx
    const int tid = threadIdx.x;
    const int w = tid >> 6;
    const int lane = tid & 63;
    const int quad = lane >> 4;
    const int cl = lane & 15;
    const int q0 = t32 * 32;
    const int row0 = q0 + w * 16;
    const int jtmax = t32 >> 1;              // same for both waves

    const unsigned short* Qh = qb + (size_t)bh * 2048 * 64;
    const unsigned short* Kh = kb + (size_t)bh * 2048 * 64;
    const unsigned short* Vh = vtb + (size_t)bh * 64 * 2048;
    float* attnh = attn + (size_t)bh * 2048 * 2048;

    // Q fragments (A-operand): lane holds Q[row0+cl][kc*32 + quad*8 + j]
    short8 aq0 = *(const short8*)(Qh + (size_t)(row0 + cl) * 64 + quad * 8);
    short8 aq1 = *(const short8*)(Qh + (size_t)(row0 + cl) * 64 + 32 + quad * 8);

    // exp(s/32 + m*(j-i)) == exp2(s*C1 + M2*(j-i)); identical formula in both
    // trips so row sums normalize exactly.
    const float LOG2E = 1.44269504088896f;
    const float C1 = LOG2E / 32.0f;                         // log2e/sqrt(1024)
    const float M2 = exp2f(-0.5f * (float)(h + 1)) * LOG2E; // slope*log2e

    auto loadK = [&](int jt, short8 (&kf)[8]) {
#pragma unroll
        for (int nt = 0; nt < 4; ++nt) {
            const unsigned short* Kp = Kh + (size_t)(jt * 64 + nt * 16 + cl) * 64 + quad * 8;
            kf[nt * 2] = *(const short8*)(Kp);
            kf[nt * 2 + 1] = *(const short8*)(Kp + 32);
        }
    };

    // ---- trip 1: row sums of exp(score) (max-free: |score| is O(1))
    float rsum[4] = {0.f, 0.f, 0.f, 0.f};
    auto tile1 = [&](int jt, const short8 (&kf)[8]) {
        const int j0 = jt * 64;
#pragma unroll
        for (int nt = 0; nt < 4; ++nt) {
            f32x4 s = {0.f, 0.f, 0.f, 0.f};
            s = __builtin_amdgcn_mfma_f32_16x16x32_bf16(aq0, kf[nt * 2], s, 0, 0, 0);
            s = __builtin_amdgcn_mfma_f32_16x16x32_bf16(aq1, kf[nt * 2 + 1], s, 0, 0, 0);
            const int jc = j0 + nt * 16 + cl;
#pragma unroll
            for (int rg = 0; rg < 4; ++rg) {
                int irow = row0 + quad * 4 + rg;
                if (jc <= irow)
                    rsum[rg] += exp2f(s[rg] * C1 + M2 * (float)(jc - irow));
            }
        }
    };

    {   // explicit register double-buffer (statically indexed; fits in 128 VGPR now)
        short8 kf0[8], kf1[8];
        loadK(0, kf0);
        int jt = 0;
        for (;;) {
            if (jt < jtmax) loadK(jt + 1, kf1);
            tile1(jt, kf0);
            if (++jt > jtmax) break;
            if (jt < jtmax) loadK(jt + 1, kf0);
            tile1(jt, kf1);
            if (++jt > jtmax) break;
        }
    }
#pragma unroll
    for (int rg = 0; rg < 4; ++rg) {
        float v = rsum[rg];
        v += __shfl_xor(v, 1);
        v += __shfl_xor(v, 2);
        v += __shfl_xor(v, 4);
        v += __shfl_xor(v, 8);
        rsum[rg] = 1.0f / v;   // inv row-sum, valid on every lane of the quad
    }

    // ---- trip 2: recompute, normalize, emit attn, accumulate O = P @ V
    // Pipeline: V issued at tile top (hides under QK/exp); K for jt+1 reloaded
    // right after the QK consumers (hides under exp/stores/PV).
    __shared__ unsigned short Ps[2][16][72];  // per-wave P strip, C-layout -> A-layout
    f32x4 oacc[4] = {};
    short8 kf[8], vf[8];
    loadK(0, kf);
    for (int jt = 0; jt <= jtmax; ++jt) {
        const int j0 = jt * 64;
#pragma unroll
        for (int on = 0; on < 4; ++on) {
            const unsigned short* Vp = Vh + (size_t)(on * 16 + cl) * 2048 + j0 + quad * 8;
            vf[on * 2] = *(const short8*)(Vp);
            vf[on * 2 + 1] = *(const short8*)(Vp + 32);
        }
#pragma unroll
        for (int nt = 0; nt < 4; ++nt) {
            f32x4 s = {0.f, 0.f, 0.f, 0.f};
            s = __builtin_amdgcn_mfma_f32_16x16x32_bf16(aq0, kf[nt * 2], s, 0, 0, 0);
            s = __builtin_amdgcn_mfma_f32_16x16x32_bf16(aq1, kf[nt * 2 + 1], s, 0, 0, 0);
            const int jc = j0 + nt * 16 + cl;
#pragma unroll
            for (int rg = 0; rg < 4; ++rg) {
                const int irow = row0 + quad * 4 + rg;
                float p = (jc <= irow)
                              ? exp2f(s[rg] * C1 + M2 * (float)(jc - irow)) * rsum[rg]
                              : 0.f;
                Ps[w][quad * 4 + rg][nt * 16 + cl] = f2bf(p);
                // attn store straight from C-layout: per instruction the 16
                // cl-lanes of each quad cover one FULL 64B line (4 rows/instr).
                __builtin_nontemporal_store(p, attnh + (size_t)irow * 2048 + jc);
            }
        }
        if (jt < jtmax) loadK(jt + 1, kf);  // kf fully consumed above (WAR ok)

        // P strip: A-operand fragments (lane = row cl, k contiguous)
        short8 pa0 = *(const short8*)&Ps[w][cl][quad * 8];
        short8 pa1 = *(const short8*)&Ps[w][cl][32 + quad * 8];

        // O += P @ V   (B-operand: vT[n][k] contiguous in k; vf issued at top)
#pragma unroll
        for (int on = 0; on < 4; ++on) {
            oacc[on] = __builtin_amdgcn_mfma_f32_16x16x32_bf16(pa0, vf[on * 2], oacc[on], 0, 0, 0);
            oacc[on] = __builtin_amdgcn_mfma_f32_16x16x32_bf16(pa1, vf[on * 2 + 1], oacc[on], 0, 0, 0);
        }
    }

    // O epilogue: out[b, s, h*64 + d]
#pragma unroll
    for (int on = 0; on < 4; ++on) {
#pragma unroll
        for (int rg = 0; rg < 4; ++rg) {
            int srow = row0 + quad * 4 + rg;
            out_[((size_t)b * 2048 + srow) * 1024 + h * 64 + on * 16 + cl] = oacc[on][rg];
        }
    }

    // zero-fill strictly-future columns (d_out is poisoned, zeros must be written)
    const int jz = (jtmax + 1) * 64;
    if (jz < 2048) {
        f32x4 z = {0.f, 0.f, 0.f, 0.f};
        for (int rr = 0; rr < 16; ++rr) {
            float* dst = attnh + (size_t)(row0 + rr) * 2048;
            for (int c = jz + lane * 4; c < 2048; c += 256)
                __builtin_nontemporal_store(z, (f32x4*)(dst + c));
        }
    }
}

// ---------------------------------------------------------------- launch
extern "C" void kernel_launch(void* const* d_in, const int* in_sizes, int n_in,
                              void* d_out, int out_size, void* d_ws, size_t ws_size,
                              hipStream_t stream) {
    const float* x = (const float*)d_in[0];     // [2,2048,1024]
    const float* Wk = (const float*)d_in[1];    // [1024,3072]
    float* out = (float*)d_out;                 // [2,2048,1024] fp32
    float* attn = out + (size_t)2 * 2048 * 1024;  // [2,16,2048,2048] fp32

    unsigned short* xb = (unsigned short*)d_ws;                 // 8 MB
    unsigned short* wtb = xb + (size_t)4096 * 1024;             // 6 MB
    unsigned short* qb = wtb + (size_t)3072 * 1024;             // 8 MB
    unsigned short* kb = qb + (size_t)32 * 2048 * 64;           // 8 MB
    unsigned short* vtb = kb + (size_t)32 * 2048 * 64;          // 8 MB

    cvt_x_kernel<<<dim3(4096), dim3(256), 0, stream>>>(x, xb, 4096 * 1024 / 4);
    cvt_wt_kernel<<<dim3(48, 16), dim3(256), 0, stream>>>(Wk, wtb);
    gemm_kqv_kernel<<<dim3(24, 32), dim3(256), 0, stream>>>(xb, wtb, qb, kb, vtb);
    attn_kernel<<<dim3(64, 16, 2), dim3(128), 0, stream>>>(qb, kb, vtb, out, attn);
}

// Round 2
// 755.722 us; speedup vs baseline: 1.1581x; 1.0519x over previous
//
#include <hip/hip_runtime.h>
#include <hip/hip_bf16.h>

typedef __attribute__((ext_vector_type(8))) short short8;
typedef __attribute__((ext_vector_type(4))) float f32x4;

// fp32 -> bf16 RNE
static __device__ __forceinline__ unsigned short f2bf(float f) {
    unsigned int x = __float_as_uint(f);
    x += 0x7fffu + ((x >> 16) & 1u);
    return (unsigned short)(x >> 16);
}

// async global->LDS, 16B per lane. LDS dest = wave-uniform base + lane*16.
static __device__ __forceinline__ void gld_lds16(const unsigned short* g, unsigned short* l) {
    __builtin_amdgcn_global_load_lds((const __attribute__((address_space(1))) void*)g,
                                     (__attribute__((address_space(3))) void*)l, 16, 0, 0);
}

// ---------------------------------------------------------------- converts
__global__ __launch_bounds__(256) void cvt_x_kernel(const float* __restrict__ in,
                                                    unsigned short* __restrict__ outb,
                                                    int n4) {
    int i = blockIdx.x * 256 + threadIdx.x;
    if (i < n4) {
        f32x4 v = *(const f32x4*)(in + (size_t)i * 4);
        ushort4 o;
        o.x = f2bf(v[0]); o.y = f2bf(v[1]); o.z = f2bf(v[2]); o.w = f2bf(v[3]);
        *(ushort4*)(outb + (size_t)i * 4) = o;
    }
}

// W [1024 x 3072] fp32  ->  WT [3072 x 1024] bf16   (tiled LDS transpose)
__global__ __launch_bounds__(256) void cvt_wt_kernel(const float* __restrict__ W,
                                                     unsigned short* __restrict__ WT) {
    __shared__ float t[64][65];
    const int n0 = blockIdx.x * 64;   // 48
    const int k0 = blockIdx.y * 64;   // 16
    const int tid = threadIdx.x;
#pragma unroll
    for (int i = 0; i < 16; ++i) {
        int lin = tid + i * 256;
        int rr = lin >> 6, cc = lin & 63;
        t[rr][cc] = W[(size_t)(k0 + rr) * 3072 + n0 + cc];
    }
    __syncthreads();
#pragma unroll
    for (int i = 0; i < 16; ++i) {
        int lin = tid + i * 256;
        int nn = lin >> 6, kk = lin & 63;
        WT[(size_t)(n0 + nn) * 1024 + k0 + kk] = f2bf(t[kk][nn]);
    }
}

// ---------------------------------------------------------------- GEMM
// C[4096,3072] = A[4096,1024] @ W[1024,3072], operands [rows,K] bf16.
// m97 structure: global_load_lds width=16 into LINEAR [128][64] LDS tiles.
// Bank-conflict fix (rule 21, both-sides): LDS stays linear; the GLOBAL
// source is chunk-permuted (chunk ^= row&7, row&7 == lane>>3 here), and the
// ds_read column applies the matching XOR -> 16-way conflict becomes 2-way.
// Bijective XCD swizzle on the 768-block grid (768 % 8 == 0).
__global__ __launch_bounds__(256) void gemm_kqv_kernel(
    const unsigned short* __restrict__ A,   // xb  [4096,1024]
    const unsigned short* __restrict__ BT,  // WTb [3072,1024]
    unsigned short* __restrict__ qb,
    unsigned short* __restrict__ kb,
    unsigned short* __restrict__ vtb) {
    __shared__ __attribute__((aligned(16))) unsigned short smem[2 * 128 * 72];  // 36864 B
    unsigned short (*As)[64] = (unsigned short(*)[64])smem;             // 16 KB
    unsigned short (*Bs)[64] = (unsigned short(*)[64])(smem + 128 * 64);
    const int tid = threadIdx.x;
    const int w = tid >> 6, lane = tid & 63;
    const int quad = lane >> 4, cl = lane & 15;

    // XCD-aware bijective swizzle: 8 XCDs x 96 contiguous tiles each
    const int wg = (int)blockIdx.x + 24 * (int)blockIdx.y;   // 0..767
    const int wgs = (wg & 7) * 96 + (wg >> 3);
    const int m0 = (wgs / 24) * 128, n0 = (wgs % 24) * 128;
    const int wm = (w >> 1) * 64, wn = (w & 1) * 64;

    // staging: wave w covers rows [w*32, w*32+32), 8 rows / instr.
    // global chunk pre-swizzled: chunk = (lane&7) ^ (lane>>3)  (row&7 == lane>>3)
    const int srow = lane >> 3;
    const int schk = (lane & 7) ^ srow;
    const unsigned short* Ap = A + (size_t)(m0 + w * 32 + srow) * 1024 + schk * 8;
    const unsigned short* Bp = BT + (size_t)(n0 + w * 32 + srow) * 1024 + schk * 8;

    f32x4 acc[4][4] = {};

    for (int kk = 0; kk < 1024; kk += 64) {
#pragma unroll
        for (int i = 0; i < 4; ++i) {
            gld_lds16(Ap + kk + (size_t)i * 8 * 1024, &As[w * 32 + i * 8][0]);
            gld_lds16(Bp + kk + (size_t)i * 8 * 1024, &Bs[w * 32 + i * 8][0]);
        }
        __syncthreads();   // drains vmcnt -> LDS tiles complete
#pragma unroll
        for (int kc = 0; kc < 2; ++kc) {
            short8 af[4], bfr[4];
#pragma unroll
            for (int i = 0; i < 4; ++i) {
                // logical chunk 4kc+quad of row (..+cl), stored at chunk^(cl&7)
                const int col = ((kc * 4 + quad) ^ (cl & 7)) * 8;
                af[i] = *(const short8*)&As[wm + i * 16 + cl][col];
                bfr[i] = *(const short8*)&Bs[wn + i * 16 + cl][col];
            }
#pragma unroll
            for (int im = 0; im < 4; ++im)
#pragma unroll
                for (int in = 0; in < 4; ++in)
                    acc[im][in] = __builtin_amdgcn_mfma_f32_16x16x32_bf16(
                        af[im], bfr[in], acc[im][in], 0, 0, 0);
        }
        __syncthreads();
    }
    // k-loop ended with __syncthreads(): safe to reuse smem as C-tile staging.
    unsigned short (*Cs)[130] = (unsigned short(*)[130])smem;  // 33280 B <= 36864 B

    const int chunk = n0 >> 10;           // 0:k 1:q 2:v (jnp.split order)
    const int d0 = n0 & 1023;
    const int b = m0 >> 11;               // tile never crosses batch boundary
    const int s_base = m0 & 2047;

    if (chunk == 2) {
        // stage TRANSPOSED: Cs[d-idx][s-idx]
#pragma unroll
        for (int im = 0; im < 4; ++im)
#pragma unroll
            for (int in = 0; in < 4; ++in)
#pragma unroll
                for (int rg = 0; rg < 4; ++rg)
                    Cs[wn + in * 16 + cl][wm + im * 16 + quad * 4 + rg] =
                        f2bf(acc[im][in][rg]);
        __syncthreads();
#pragma unroll
        for (int it = 0; it < 8; ++it) {
            int l = it * 2048 + tid * 8;
            int c = l >> 7;               // d-index 0..127
            int r = l & 127;              // s-offset (multiple of 8)
            int d = d0 + c, hh = d >> 6, dd = d & 63;
            size_t dst = ((size_t)(b * 16 + hh) * 64 + dd) * 2048 + s_base + r;
            *(uint4*)(vtb + dst) = *(const uint4*)&Cs[c][r];
        }
    } else {
#pragma unroll
        for (int im = 0; im < 4; ++im)
#pragma unroll
            for (int in = 0; in < 4; ++in)
#pragma unroll
                for (int rg = 0; rg < 4; ++rg)
                    Cs[wm + im * 16 + quad * 4 + rg][wn + in * 16 + cl] =
                        f2bf(acc[im][in][rg]);
        __syncthreads();
        unsigned short* outp = (chunk == 0) ? kb : qb;
#pragma unroll
        for (int it = 0; it < 8; ++it) {
            int l = it * 2048 + tid * 8;
            int r = l >> 7;               // s-offset
            int c = l & 127;              // d-index (multiple of 8)
            int d = d0 + c, hh = d >> 6, dd = d & 63;
            size_t dst = ((size_t)(b * 16 + hh) * 2048 + s_base + r) * 64 + dd;
            *(uint4*)(outp + dst) = *(const uint4*)&Cs[r][c];
        }
    }
}

// ---------------------------------------------------------------- fused attention
// grid: (64, h=16, b=2); block 128 = 2 waves x 16 q-rows (32-row q-tile).
// Both waves of a block have IDENTICAL tile count (jtmax = t32>>1).
// t32 swizzled by 37x+11hb so consecutive block ids carry well-spread work.
// __launch_bounds__(128, 3): VGPR cap 170 -- trip-2 peak liveness is ~135
// (kf 32 + vf 32 + aq 16 + oacc 16 + sv 16 + misc); the previous (128,4)
// cap of 128 forced per-tile scratch spills. 12 waves/CU, spill-free.
__global__ __launch_bounds__(128, 3) void attn_kernel(
    const unsigned short* __restrict__ qb,   // [B,H,S,64]
    const unsigned short* __restrict__ kb,   // [B,H,S,64]
    const unsigned short* __restrict__ vtb,  // [B,H,64,S]
    float* __restrict__ out_,                // [B,S,1024]
    float* __restrict__ attn) {              // [B,H,S,S]
    const int h = blockIdx.y;
    const int b = blockIdx.z;
    const int bh = b * 16 + h;
    const int t32 = (37 * (int)blockIdx.x + 11 * bh) & 63;  // 32-row tile idx
    const int tid = threadIdx.x;
    const int w = tid >> 6;
    const int lane = tid & 63;
    const int quad = lane >> 4;
    const int cl = lane & 15;
    const int q0 = t32 * 32;
    const int row0 = q0 + w * 16;
    const int jtmax = t32 >> 1;              // same for both waves

    const unsigned short* Qh = qb + (size_t)bh * 2048 * 64;
    const unsigned short* Kh = kb + (size_t)bh * 2048 * 64;
    const unsigned short* Vh = vtb + (size_t)bh * 64 * 2048;
    float* attnh = attn + (size_t)bh * 2048 * 2048;

    // Q fragments (A-operand): lane holds Q[row0+cl][kc*32 + quad*8 + j]
    short8 aq0 = *(const short8*)(Qh + (size_t)(row0 + cl) * 64 + quad * 8);
    short8 aq1 = *(const short8*)(Qh + (size_t)(row0 + cl) * 64 + 32 + quad * 8);

    // exp(s/32 + m*(j-i)) == exp2(s*C1 + M2*(j-i)); identical formula in both
    // trips so row sums normalize exactly.
    const float LOG2E = 1.44269504088896f;
    const float C1 = LOG2E / 32.0f;                         // log2e/sqrt(1024)
    const float M2 = exp2f(-0.5f * (float)(h + 1)) * LOG2E; // slope*log2e

    auto loadK = [&](int jt, short8 (&kf)[8]) {
#pragma unroll
        for (int nt = 0; nt < 4; ++nt) {
            const unsigned short* Kp = Kh + (size_t)(jt * 64 + nt * 16 + cl) * 64 + quad * 8;
            kf[nt * 2] = *(const short8*)(Kp);
            kf[nt * 2 + 1] = *(const short8*)(Kp + 32);
        }
    };

    // ---- trip 1: row sums of exp(score) (max-free: |score| is O(1))
    float rsum[4] = {0.f, 0.f, 0.f, 0.f};
    auto tile1 = [&](int jt, const short8 (&kf)[8]) {
        const int j0 = jt * 64;
#pragma unroll
        for (int nt = 0; nt < 4; ++nt) {
            f32x4 s = {0.f, 0.f, 0.f, 0.f};
            s = __builtin_amdgcn_mfma_f32_16x16x32_bf16(aq0, kf[nt * 2], s, 0, 0, 0);
            s = __builtin_amdgcn_mfma_f32_16x16x32_bf16(aq1, kf[nt * 2 + 1], s, 0, 0, 0);
            const int jc = j0 + nt * 16 + cl;
#pragma unroll
            for (int rg = 0; rg < 4; ++rg) {
                int irow = row0 + quad * 4 + rg;
                if (jc <= irow)
                    rsum[rg] += exp2f(s[rg] * C1 + M2 * (float)(jc - irow));
            }
        }
    };

    {   // register double-buffer (statically indexed; spill-free under 170 cap)
        short8 kf0[8], kf1[8];
        loadK(0, kf0);
        int jt = 0;
        for (;;) {
            if (jt < jtmax) loadK(jt + 1, kf1);
            tile1(jt, kf0);
            if (++jt > jtmax) break;
            if (jt < jtmax) loadK(jt + 1, kf0);
            tile1(jt, kf1);
            if (++jt > jtmax) break;
        }
    }
#pragma unroll
    for (int rg = 0; rg < 4; ++rg) {
        float v = rsum[rg];
        v += __shfl_xor(v, 1);
        v += __shfl_xor(v, 2);
        v += __shfl_xor(v, 4);
        v += __shfl_xor(v, 8);
        rsum[rg] = 1.0f / v;   // inv row-sum, valid on every lane of the quad
    }

    // ---- trip 2: recompute, normalize, emit attn, accumulate O = P @ V
    // Per-tile order (minimizes peak liveness + hides latency):
    //   V(jt) issue -> QK(kf) -> K(jt+1) reload in-place (kf consumed) ->
    //   exp/attn-store/Ps-write -> Ps read -> PV.
    __shared__ unsigned short Ps[2][16][72];  // per-wave P strip, C-layout -> A-layout
    f32x4 oacc[4] = {};
    short8 kf[8], vf[8];
    loadK(0, kf);
    for (int jt = 0; jt <= jtmax; ++jt) {
        const int j0 = jt * 64;
#pragma unroll
        for (int on = 0; on < 4; ++on) {
            const unsigned short* Vp = Vh + (size_t)(on * 16 + cl) * 2048 + j0 + quad * 8;
            vf[on * 2] = *(const short8*)(Vp);
            vf[on * 2 + 1] = *(const short8*)(Vp + 32);
        }
        // QK for all 4 column-tiles first (kf fully consumed before reload)
        f32x4 sv[4];
#pragma unroll
        for (int nt = 0; nt < 4; ++nt) {
            f32x4 s = {0.f, 0.f, 0.f, 0.f};
            s = __builtin_amdgcn_mfma_f32_16x16x32_bf16(aq0, kf[nt * 2], s, 0, 0, 0);
            sv[nt] = __builtin_amdgcn_mfma_f32_16x16x32_bf16(aq1, kf[nt * 2 + 1], s, 0, 0, 0);
        }
        if (jt < jtmax) loadK(jt + 1, kf);  // in-place: hides under exp/stores

#pragma unroll
        for (int nt = 0; nt < 4; ++nt) {
            const int jc = j0 + nt * 16 + cl;
#pragma unroll
            for (int rg = 0; rg < 4; ++rg) {
                const int irow = row0 + quad * 4 + rg;
                float p = (jc <= irow)
                              ? exp2f(sv[nt][rg] * C1 + M2 * (float)(jc - irow)) * rsum[rg]
                              : 0.f;
                Ps[w][quad * 4 + rg][nt * 16 + cl] = f2bf(p);
                // attn store straight from C-layout: the 16 cl-lanes of each
                // quad cover one FULL 64B segment (4 rows per instruction).
                __builtin_nontemporal_store(p, attnh + (size_t)irow * 2048 + jc);
            }
        }

        // P strip: A-operand fragments (lane = row cl, k contiguous)
        short8 pa0 = *(const short8*)&Ps[w][cl][quad * 8];
        short8 pa1 = *(const short8*)&Ps[w][cl][32 + quad * 8];

        // O += P @ V   (B-operand: vT[n][k] contiguous in k; vf issued at top)
#pragma unroll
        for (int on = 0; on < 4; ++on) {
            oacc[on] = __builtin_amdgcn_mfma_f32_16x16x32_bf16(pa0, vf[on * 2], oacc[on], 0, 0, 0);
            oacc[on] = __builtin_amdgcn_mfma_f32_16x16x32_bf16(pa1, vf[on * 2 + 1], oacc[on], 0, 0, 0);
        }
    }

    // O epilogue: out[b, s, h*64 + d]  (quad covers a 64B contiguous segment)
#pragma unroll
    for (int on = 0; on < 4; ++on) {
#pragma unroll
        for (int rg = 0; rg < 4; ++rg) {
            int srow = row0 + quad * 4 + rg;
            __builtin_nontemporal_store(
                oacc[on][rg], out_ + ((size_t)b * 2048 + srow) * 1024 + h * 64 + on * 16 + cl);
        }
    }

    // zero-fill strictly-future columns (d_out is poisoned, zeros must be written)
    const int jz = (jtmax + 1) * 64;
    if (jz < 2048) {
        f32x4 z = {0.f, 0.f, 0.f, 0.f};
        for (int rr = 0; rr < 16; ++rr) {
            float* dst = attnh + (size_t)(row0 + rr) * 2048;
            for (int c = jz + lane * 4; c < 2048; c += 256)
                __builtin_nontemporal_store(z, (f32x4*)(dst + c));
        }
    }
}

// ---------------------------------------------------------------- launch
extern "C" void kernel_launch(void* const* d_in, const int* in_sizes, int n_in,
                              void* d_out, int out_size, void* d_ws, size_t ws_size,
                              hipStream_t stream) {
    const float* x = (const float*)d_in[0];     // [2,2048,1024]
    const float* Wk = (const float*)d_in[1];    // [1024,3072]
    float* out = (float*)d_out;                 // [2,2048,1024] fp32
    float* attn = out + (size_t)2 * 2048 * 1024;  // [2,16,2048,2048] fp32

    unsigned short* xb = (unsigned short*)d_ws;                 // 8 MB
    unsigned short* wtb = xb + (size_t)4096 * 1024;             // 6 MB
    unsigned short* qb = wtb + (size_t)3072 * 1024;             // 8 MB
    unsigned short* kb = qb + (size_t)32 * 2048 * 64;           // 8 MB
    unsigned short* vtb = kb + (size_t)32 * 2048 * 64;          // 8 MB

    cvt_x_kernel<<<dim3(4096), dim3(256), 0, stream>>>(x, xb, 4096 * 1024 / 4);
    cvt_wt_kernel<<<dim3(48, 16), dim3(256), 0, stream>>>(Wk, wtb);
    gemm_kqv_kernel<<<dim3(24, 32), dim3(256), 0, stream>>>(xb, wtb, qb, kb, vtb);
    attn_kernel<<<dim3(64, 16, 2), dim3(128), 0, stream>>>(qb, kb, vtb, out, attn);
}

// Round 3
// 703.231 us; speedup vs baseline: 1.2445x; 1.0746x over previous
//
#include <hip/hip_runtime.h>
#include <hip/hip_bf16.h>

typedef __attribute__((ext_vector_type(8))) short short8;
typedef __attribute__((ext_vector_type(4))) float f32x4;

// fp32 -> bf16 RNE
static __device__ __forceinline__ unsigned short f2bf(float f) {
    unsigned int x = __float_as_uint(f);
    x += 0x7fffu + ((x >> 16) & 1u);
    return (unsigned short)(x >> 16);
}

// async global->LDS, 16B per lane. LDS dest = wave-uniform base + lane*16.
static __device__ __forceinline__ void gld_lds16(const unsigned short* g, unsigned short* l) {
    __builtin_amdgcn_global_load_lds((const __attribute__((address_space(1))) void*)g,
                                     (__attribute__((address_space(3))) void*)l, 16, 0, 0);
}

// ---------------------------------------------------------------- converts
__global__ __launch_bounds__(256) void cvt_x_kernel(const float* __restrict__ in,
                                                    unsigned short* __restrict__ outb,
                                                    int n4) {
    int i = blockIdx.x * 256 + threadIdx.x;
    if (i < n4) {
        f32x4 v = *(const f32x4*)(in + (size_t)i * 4);
        ushort4 o;
        o.x = f2bf(v[0]); o.y = f2bf(v[1]); o.z = f2bf(v[2]); o.w = f2bf(v[3]);
        *(ushort4*)(outb + (size_t)i * 4) = o;
    }
}

// W [1024 x 3072] fp32  ->  WT [3072 x 1024] bf16   (tiled LDS transpose)
__global__ __launch_bounds__(256) void cvt_wt_kernel(const float* __restrict__ W,
                                                     unsigned short* __restrict__ WT) {
    __shared__ float t[64][65];
    const int n0 = blockIdx.x * 64;   // 48
    const int k0 = blockIdx.y * 64;   // 16
    const int tid = threadIdx.x;
#pragma unroll
    for (int i = 0; i < 16; ++i) {
        int lin = tid + i * 256;
        int rr = lin >> 6, cc = lin & 63;
        t[rr][cc] = W[(size_t)(k0 + rr) * 3072 + n0 + cc];
    }
    __syncthreads();
#pragma unroll
    for (int i = 0; i < 16; ++i) {
        int lin = tid + i * 256;
        int nn = lin >> 6, kk = lin & 63;
        WT[(size_t)(n0 + nn) * 1024 + k0 + kk] = f2bf(t[kk][nn]);
    }
}

// ---------------------------------------------------------------- GEMM
// C[4096,3072] = A[4096,1024] @ W[1024,3072], operands [rows,K] bf16.
// m97 structure: global_load_lds width=16 into LINEAR [128][64] LDS tiles.
// Bank-conflict fix (rule 21, both-sides): LDS stays linear; the GLOBAL
// source is chunk-permuted (chunk ^= row&7, row&7 == lane>>3 here), and the
// ds_read column applies the matching XOR -> 16-way conflict becomes 2-way.
// Bijective XCD swizzle on the 768-block grid (768 % 8 == 0).
__global__ __launch_bounds__(256) void gemm_kqv_kernel(
    const unsigned short* __restrict__ A,   // xb  [4096,1024]
    const unsigned short* __restrict__ BT,  // WTb [3072,1024]
    unsigned short* __restrict__ qb,
    unsigned short* __restrict__ kb,
    unsigned short* __restrict__ vtb) {
    __shared__ __attribute__((aligned(16))) unsigned short smem[2 * 128 * 72];  // 36864 B
    unsigned short (*As)[64] = (unsigned short(*)[64])smem;             // 16 KB
    unsigned short (*Bs)[64] = (unsigned short(*)[64])(smem + 128 * 64);
    const int tid = threadIdx.x;
    const int w = tid >> 6, lane = tid & 63;
    const int quad = lane >> 4, cl = lane & 15;

    // XCD-aware bijective swizzle: 8 XCDs x 96 contiguous tiles each
    const int wg = (int)blockIdx.x + 24 * (int)blockIdx.y;   // 0..767
    const int wgs = (wg & 7) * 96 + (wg >> 3);
    const int m0 = (wgs / 24) * 128, n0 = (wgs % 24) * 128;
    const int wm = (w >> 1) * 64, wn = (w & 1) * 64;

    // staging: wave w covers rows [w*32, w*32+32), 8 rows / instr.
    // global chunk pre-swizzled: chunk = (lane&7) ^ (lane>>3)  (row&7 == lane>>3)
    const int srow = lane >> 3;
    const int schk = (lane & 7) ^ srow;
    const unsigned short* Ap = A + (size_t)(m0 + w * 32 + srow) * 1024 + schk * 8;
    const unsigned short* Bp = BT + (size_t)(n0 + w * 32 + srow) * 1024 + schk * 8;

    f32x4 acc[4][4] = {};

    for (int kk = 0; kk < 1024; kk += 64) {
#pragma unroll
        for (int i = 0; i < 4; ++i) {
            gld_lds16(Ap + kk + (size_t)i * 8 * 1024, &As[w * 32 + i * 8][0]);
            gld_lds16(Bp + kk + (size_t)i * 8 * 1024, &Bs[w * 32 + i * 8][0]);
        }
        __syncthreads();   // drains vmcnt -> LDS tiles complete
#pragma unroll
        for (int kc = 0; kc < 2; ++kc) {
            short8 af[4], bfr[4];
#pragma unroll
            for (int i = 0; i < 4; ++i) {
                // logical chunk 4kc+quad of row (..+cl), stored at chunk^(cl&7)
                const int col = ((kc * 4 + quad) ^ (cl & 7)) * 8;
                af[i] = *(const short8*)&As[wm + i * 16 + cl][col];
                bfr[i] = *(const short8*)&Bs[wn + i * 16 + cl][col];
            }
#pragma unroll
            for (int im = 0; im < 4; ++im)
#pragma unroll
                for (int in = 0; in < 4; ++in)
                    acc[im][in] = __builtin_amdgcn_mfma_f32_16x16x32_bf16(
                        af[im], bfr[in], acc[im][in], 0, 0, 0);
        }
        __syncthreads();
    }
    // k-loop ended with __syncthreads(): safe to reuse smem as C-tile staging.
    unsigned short (*Cs)[130] = (unsigned short(*)[130])smem;  // 33280 B <= 36864 B

    const int chunk = n0 >> 10;           // 0:k 1:q 2:v (jnp.split order)
    const int d0 = n0 & 1023;
    const int b = m0 >> 11;               // tile never crosses batch boundary
    const int s_base = m0 & 2047;

    if (chunk == 2) {
        // stage TRANSPOSED: Cs[d-idx][s-idx]
#pragma unroll
        for (int im = 0; im < 4; ++im)
#pragma unroll
            for (int in = 0; in < 4; ++in)
#pragma unroll
                for (int rg = 0; rg < 4; ++rg)
                    Cs[wn + in * 16 + cl][wm + im * 16 + quad * 4 + rg] =
                        f2bf(acc[im][in][rg]);
        __syncthreads();
#pragma unroll
        for (int it = 0; it < 8; ++it) {
            int l = it * 2048 + tid * 8;
            int c = l >> 7;               // d-index 0..127
            int r = l & 127;              // s-offset (multiple of 8)
            int d = d0 + c, hh = d >> 6, dd = d & 63;
            size_t dst = ((size_t)(b * 16 + hh) * 64 + dd) * 2048 + s_base + r;
            *(uint4*)(vtb + dst) = *(const uint4*)&Cs[c][r];
        }
    } else {
#pragma unroll
        for (int im = 0; im < 4; ++im)
#pragma unroll
            for (int in = 0; in < 4; ++in)
#pragma unroll
                for (int rg = 0; rg < 4; ++rg)
                    Cs[wm + im * 16 + quad * 4 + rg][wn + in * 16 + cl] =
                        f2bf(acc[im][in][rg]);
        __syncthreads();
        unsigned short* outp = (chunk == 0) ? kb : qb;
#pragma unroll
        for (int it = 0; it < 8; ++it) {
            int l = it * 2048 + tid * 8;
            int r = l >> 7;               // s-offset
            int c = l & 127;              // d-index (multiple of 8)
            int d = d0 + c, hh = d >> 6, dd = d & 63;
            size_t dst = ((size_t)(b * 16 + hh) * 2048 + s_base + r) * 64 + dd;
            *(uint4*)(outp + dst) = *(const uint4*)&Cs[r][c];
        }
    }
}

// ---------------------------------------------------------------- fused attention
// v3: grid (32, 16, 2); block 256 = 4 waves x 16 q-rows (64-row q-tile).
// K and V tiles staged ONCE per block into LDS via global_load_lds (XOR-
// swizzled source, matching XOR on ds_read -> conflict-free), shared by all
// 4 waves: 4x less L2 traffic than per-wave register loads, and the 64-VGPR
// K/V arrays are gone -> __launch_bounds__(256,4) (128-VGPR cap, 16 waves/CU)
// holds without spills. 2-barrier-per-tile (proven m97 pattern); cross-block
// overlap at 4 blocks/CU hides the barrier drain.
// LPT swizzle: t64 = (23*bx + 7*bh) & 31 (bijective per bh).
__global__ __launch_bounds__(256, 4) void attn_kernel(
    const unsigned short* __restrict__ qb,   // [B,H,S,64]
    const unsigned short* __restrict__ kb,   // [B,H,S,64]
    const unsigned short* __restrict__ vtb,  // [B,H,64,S]
    float* __restrict__ out_,                // [B,S,1024]
    float* __restrict__ attn) {              // [B,H,S,S]
    const int h = blockIdx.y;
    const int b = blockIdx.z;
    const int bh = b * 16 + h;
    const int t64 = (23 * (int)blockIdx.x + 7 * bh) & 31;   // 64-row tile idx
    const int tid = threadIdx.x;
    const int w = tid >> 6;
    const int lane = tid & 63;
    const int quad = lane >> 4;
    const int cl = lane & 15;
    const int q0 = t64 * 64;
    const int row0 = q0 + w * 16;
    const int jtmax = t64;                   // uniform across the block

    const unsigned short* Qh = qb + (size_t)bh * 2048 * 64;
    const unsigned short* Kh = kb + (size_t)bh * 2048 * 64;
    const unsigned short* Vh = vtb + (size_t)bh * 64 * 2048;
    float* attnh = attn + (size_t)bh * 2048 * 2048;

    __shared__ __attribute__((aligned(16))) unsigned short Kt[64][64];  // 8 KB
    __shared__ __attribute__((aligned(16))) unsigned short Vt[64][64];  // 8 KB
    __shared__ unsigned short Ps[4][16][72];                            // 9 KB

    // staging lane mapping (identical to gemm): 8 rows x 128B per instr,
    // source chunk pre-XORed so LDS slot s of row r holds chunk s^(r&7).
    const int srow = lane >> 3;
    const int schk = (lane & 7) ^ srow;

    // Q fragments (A-operand): lane holds Q[row0+cl][kc*32 + quad*8 + j]
    short8 aq0 = *(const short8*)(Qh + (size_t)(row0 + cl) * 64 + quad * 8);
    short8 aq1 = *(const short8*)(Qh + (size_t)(row0 + cl) * 64 + 32 + quad * 8);

    const float mh = exp2f(-0.5f * (float)(h + 1));  // ALiBi slope 2^-((h+1)/2)
    const float sc1 = 1.0f / 32.0f;                  // 1/sqrt(1024)

    // ---- trip 1: row sums of exp(score) (max-free: |score| is O(1))
    float rsum[4] = {0.f, 0.f, 0.f, 0.f};
    for (int jt = 0; jt <= jtmax; ++jt) {
        const int j0 = jt * 64;
#pragma unroll
        for (int i = 0; i < 2; ++i)
            gld_lds16(Kh + (size_t)(j0 + w * 16 + i * 8 + srow) * 64 + schk * 8,
                      &Kt[w * 16 + i * 8][0]);
        __syncthreads();   // drains vmcnt -> tile complete for all waves
#pragma unroll
        for (int nt = 0; nt < 4; ++nt) {
            const int r = nt * 16 + cl;
            short8 k0 = *(const short8*)&Kt[r][((quad) ^ (cl & 7)) * 8];
            short8 k1 = *(const short8*)&Kt[r][((quad + 4) ^ (cl & 7)) * 8];
            f32x4 s = {0.f, 0.f, 0.f, 0.f};
            s = __builtin_amdgcn_mfma_f32_16x16x32_bf16(aq0, k0, s, 0, 0, 0);
            s = __builtin_amdgcn_mfma_f32_16x16x32_bf16(aq1, k1, s, 0, 0, 0);
            const int jc = j0 + nt * 16 + cl;
#pragma unroll
            for (int rg = 0; rg < 4; ++rg) {
                int irow = row0 + quad * 4 + rg;
                if (jc <= irow)
                    rsum[rg] += __expf(s[rg] * sc1 + mh * (float)(jc - irow));
            }
        }
        __syncthreads();   // protect Kt before next stage
    }
#pragma unroll
    for (int rg = 0; rg < 4; ++rg) {
        float v = rsum[rg];
        v += __shfl_xor(v, 1);
        v += __shfl_xor(v, 2);
        v += __shfl_xor(v, 4);
        v += __shfl_xor(v, 8);
        rsum[rg] = 1.0f / v;   // inv row-sum, valid on every lane of the quad
    }

    // ---- trip 2: recompute, normalize, emit attn, accumulate O = P @ V
    f32x4 oacc[4] = {};
    for (int jt = 0; jt <= jtmax; ++jt) {
        const int j0 = jt * 64;
#pragma unroll
        for (int i = 0; i < 2; ++i) {
            gld_lds16(Kh + (size_t)(j0 + w * 16 + i * 8 + srow) * 64 + schk * 8,
                      &Kt[w * 16 + i * 8][0]);
            gld_lds16(Vh + (size_t)(w * 16 + i * 8 + srow) * 2048 + j0 + schk * 8,
                      &Vt[w * 16 + i * 8][0]);
        }
        __syncthreads();
        f32x4 sv[4];
#pragma unroll
        for (int nt = 0; nt < 4; ++nt) {
            const int r = nt * 16 + cl;
            short8 k0 = *(const short8*)&Kt[r][((quad) ^ (cl & 7)) * 8];
            short8 k1 = *(const short8*)&Kt[r][((quad + 4) ^ (cl & 7)) * 8];
            f32x4 s = {0.f, 0.f, 0.f, 0.f};
            s = __builtin_amdgcn_mfma_f32_16x16x32_bf16(aq0, k0, s, 0, 0, 0);
            sv[nt] = __builtin_amdgcn_mfma_f32_16x16x32_bf16(aq1, k1, s, 0, 0, 0);
        }
#pragma unroll
        for (int nt = 0; nt < 4; ++nt) {
            const int jc = j0 + nt * 16 + cl;
#pragma unroll
            for (int rg = 0; rg < 4; ++rg) {
                const int irow = row0 + quad * 4 + rg;
                float p = (jc <= irow)
                              ? __expf(sv[nt][rg] * sc1 + mh * (float)(jc - irow)) * rsum[rg]
                              : 0.f;
                Ps[w][quad * 4 + rg][nt * 16 + cl] = f2bf(p);
                // attn store from C-layout: 16 cl-lanes of each quad cover one
                // FULL 64B segment (4 rows per instruction).
                __builtin_nontemporal_store(p, attnh + (size_t)irow * 2048 + jc);
            }
        }

        // P strip: A-operand fragments (lane = row cl, k contiguous)
        short8 pa0 = *(const short8*)&Ps[w][cl][quad * 8];
        short8 pa1 = *(const short8*)&Ps[w][cl][32 + quad * 8];

        // O += P @ V   (B-frag: row of Vt = d-index, cols = k; swizzled read)
#pragma unroll
        for (int on = 0; on < 4; ++on) {
            const int r = on * 16 + cl;
            short8 v0 = *(const short8*)&Vt[r][((quad) ^ (cl & 7)) * 8];
            short8 v1 = *(const short8*)&Vt[r][((quad + 4) ^ (cl & 7)) * 8];
            oacc[on] = __builtin_amdgcn_mfma_f32_16x16x32_bf16(pa0, v0, oacc[on], 0, 0, 0);
            oacc[on] = __builtin_amdgcn_mfma_f32_16x16x32_bf16(pa1, v1, oacc[on], 0, 0, 0);
        }
        __syncthreads();   // protect Kt/Vt before next stage
    }

    // O epilogue: out[b, s, h*64 + d]  (quad covers a 64B contiguous segment)
#pragma unroll
    for (int on = 0; on < 4; ++on) {
#pragma unroll
        for (int rg = 0; rg < 4; ++rg) {
            int srow2 = row0 + quad * 4 + rg;
            __builtin_nontemporal_store(
                oacc[on][rg], out_ + ((size_t)b * 2048 + srow2) * 1024 + h * 64 + on * 16 + cl);
        }
    }

    // zero-fill strictly-future columns (d_out is poisoned, zeros must be written)
    const int jz = (jtmax + 1) * 64;
    if (jz < 2048) {
        f32x4 z = {0.f, 0.f, 0.f, 0.f};
        for (int rr = 0; rr < 16; ++rr) {
            float* dst = attnh + (size_t)(row0 + rr) * 2048;
            for (int c = jz + lane * 4; c < 2048; c += 256)
                __builtin_nontemporal_store(z, (f32x4*)(dst + c));
        }
    }
}

// ---------------------------------------------------------------- launch
extern "C" void kernel_launch(void* const* d_in, const int* in_sizes, int n_in,
                              void* d_out, int out_size, void* d_ws, size_t ws_size,
                              hipStream_t stream) {
    const float* x = (const float*)d_in[0];     // [2,2048,1024]
    const float* Wk = (const float*)d_in[1];    // [1024,3072]
    float* out = (float*)d_out;                 // [2,2048,1024] fp32
    float* attn = out + (size_t)2 * 2048 * 1024;  // [2,16,2048,2048] fp32

    unsigned short* xb = (unsigned short*)d_ws;                 // 8 MB
    unsigned short* wtb = xb + (size_t)4096 * 1024;             // 6 MB
    unsigned short* qb = wtb + (size_t)3072 * 1024;             // 8 MB
    unsigned short* kb = qb + (size_t)32 * 2048 * 64;           // 8 MB
    unsigned short* vtb = kb + (size_t)32 * 2048 * 64;          // 8 MB

    cvt_x_kernel<<<dim3(4096), dim3(256), 0, stream>>>(x, xb, 4096 * 1024 / 4);
    cvt_wt_kernel<<<dim3(48, 16), dim3(256), 0, stream>>>(Wk, wtb);
    gemm_kqv_kernel<<<dim3(24, 32), dim3(256), 0, stream>>>(xb, wtb, qb, kb, vtb);
    attn_kernel<<<dim3(32, 16, 2), dim3(256), 0, stream>>>(qb, kb, vtb, out, attn);
}

// Round 4
// 700.808 us; speedup vs baseline: 1.2488x; 1.0035x over previous
//
#include <hip/hip_runtime.h>
#include <hip/hip_bf16.h>

typedef __attribute__((ext_vector_type(8))) short short8;
typedef __attribute__((ext_vector_type(4))) float f32x4;

// fp32 -> bf16 RNE
static __device__ __forceinline__ unsigned short f2bf(float f) {
    unsigned int x = __float_as_uint(f);
    x += 0x7fffu + ((x >> 16) & 1u);
    return (unsigned short)(x >> 16);
}

// async global->LDS, 16B per lane. LDS dest = wave-uniform base + lane*16.
static __device__ __forceinline__ void gld_lds16(const unsigned short* g, unsigned short* l) {
    __builtin_amdgcn_global_load_lds((const __attribute__((address_space(1))) void*)g,
                                     (__attribute__((address_space(3))) void*)l, 16, 0, 0);
}

// ---------------------------------------------------------------- converts
__global__ __launch_bounds__(256) void cvt_x_kernel(const float* __restrict__ in,
                                                    unsigned short* __restrict__ outb,
                                                    int n4) {
    int i = blockIdx.x * 256 + threadIdx.x;
    if (i < n4) {
        f32x4 v = *(const f32x4*)(in + (size_t)i * 4);
        ushort4 o;
        o.x = f2bf(v[0]); o.y = f2bf(v[1]); o.z = f2bf(v[2]); o.w = f2bf(v[3]);
        *(ushort4*)(outb + (size_t)i * 4) = o;
    }
}

// W [1024 x 3072] fp32  ->  WT [3072 x 1024] bf16   (tiled LDS transpose)
__global__ __launch_bounds__(256) void cvt_wt_kernel(const float* __restrict__ W,
                                                     unsigned short* __restrict__ WT) {
    __shared__ float t[64][65];
    const int n0 = blockIdx.x * 64;   // 48
    const int k0 = blockIdx.y * 64;   // 16
    const int tid = threadIdx.x;
#pragma unroll
    for (int i = 0; i < 16; ++i) {
        int lin = tid + i * 256;
        int rr = lin >> 6, cc = lin & 63;
        t[rr][cc] = W[(size_t)(k0 + rr) * 3072 + n0 + cc];
    }
    __syncthreads();
#pragma unroll
    for (int i = 0; i < 16; ++i) {
        int lin = tid + i * 256;
        int nn = lin >> 6, kk = lin & 63;
        WT[(size_t)(n0 + nn) * 1024 + k0 + kk] = f2bf(t[kk][nn]);
    }
}

// ---------------------------------------------------------------- GEMM
// C[4096,3072] = A[4096,1024] @ W[1024,3072], operands [rows,K] bf16.
// m97 structure: global_load_lds width=16 into LINEAR [128][64] LDS tiles.
// Bank-conflict fix (rule 21, both-sides): LDS stays linear; the GLOBAL
// source is chunk-permuted (chunk ^= row&7, row&7 == lane>>3 here), and the
// ds_read column applies the matching XOR -> 16-way conflict becomes 2-way.
// Bijective XCD swizzle on the 768-block grid (768 % 8 == 0).
__global__ __launch_bounds__(256) void gemm_kqv_kernel(
    const unsigned short* __restrict__ A,   // xb  [4096,1024]
    const unsigned short* __restrict__ BT,  // WTb [3072,1024]
    unsigned short* __restrict__ qb,
    unsigned short* __restrict__ kb,
    unsigned short* __restrict__ vtb) {
    __shared__ __attribute__((aligned(16))) unsigned short smem[2 * 128 * 72];  // 36864 B
    unsigned short (*As)[64] = (unsigned short(*)[64])smem;             // 16 KB
    unsigned short (*Bs)[64] = (unsigned short(*)[64])(smem + 128 * 64);
    const int tid = threadIdx.x;
    const int w = tid >> 6, lane = tid & 63;
    const int quad = lane >> 4, cl = lane & 15;

    // XCD-aware bijective swizzle: 8 XCDs x 96 contiguous tiles each
    const int wg = (int)blockIdx.x + 24 * (int)blockIdx.y;   // 0..767
    const int wgs = (wg & 7) * 96 + (wg >> 3);
    const int m0 = (wgs / 24) * 128, n0 = (wgs % 24) * 128;
    const int wm = (w >> 1) * 64, wn = (w & 1) * 64;

    // staging: wave w covers rows [w*32, w*32+32), 8 rows / instr.
    // global chunk pre-swizzled: chunk = (lane&7) ^ (lane>>3)  (row&7 == lane>>3)
    const int srow = lane >> 3;
    const int schk = (lane & 7) ^ srow;
    const unsigned short* Ap = A + (size_t)(m0 + w * 32 + srow) * 1024 + schk * 8;
    const unsigned short* Bp = BT + (size_t)(n0 + w * 32 + srow) * 1024 + schk * 8;

    f32x4 acc[4][4] = {};

    for (int kk = 0; kk < 1024; kk += 64) {
#pragma unroll
        for (int i = 0; i < 4; ++i) {
            gld_lds16(Ap + kk + (size_t)i * 8 * 1024, &As[w * 32 + i * 8][0]);
            gld_lds16(Bp + kk + (size_t)i * 8 * 1024, &Bs[w * 32 + i * 8][0]);
        }
        __syncthreads();   // drains vmcnt -> LDS tiles complete
#pragma unroll
        for (int kc = 0; kc < 2; ++kc) {
            short8 af[4], bfr[4];
#pragma unroll
            for (int i = 0; i < 4; ++i) {
                // logical chunk 4kc+quad of row (..+cl), stored at chunk^(cl&7)
                const int col = ((kc * 4 + quad) ^ (cl & 7)) * 8;
                af[i] = *(const short8*)&As[wm + i * 16 + cl][col];
                bfr[i] = *(const short8*)&Bs[wn + i * 16 + cl][col];
            }
#pragma unroll
            for (int im = 0; im < 4; ++im)
#pragma unroll
                for (int in = 0; in < 4; ++in)
                    acc[im][in] = __builtin_amdgcn_mfma_f32_16x16x32_bf16(
                        af[im], bfr[in], acc[im][in], 0, 0, 0);
        }
        __syncthreads();
    }
    // k-loop ended with __syncthreads(): safe to reuse smem as C-tile staging.
    unsigned short (*Cs)[130] = (unsigned short(*)[130])smem;  // 33280 B <= 36864 B

    const int chunk = n0 >> 10;           // 0:k 1:q 2:v (jnp.split order)
    const int d0 = n0 & 1023;
    const int b = m0 >> 11;               // tile never crosses batch boundary
    const int s_base = m0 & 2047;

    if (chunk == 2) {
        // stage TRANSPOSED: Cs[d-idx][s-idx]
#pragma unroll
        for (int im = 0; im < 4; ++im)
#pragma unroll
            for (int in = 0; in < 4; ++in)
#pragma unroll
                for (int rg = 0; rg < 4; ++rg)
                    Cs[wn + in * 16 + cl][wm + im * 16 + quad * 4 + rg] =
                        f2bf(acc[im][in][rg]);
        __syncthreads();
#pragma unroll
        for (int it = 0; it < 8; ++it) {
            int l = it * 2048 + tid * 8;
            int c = l >> 7;               // d-index 0..127
            int r = l & 127;              // s-offset (multiple of 8)
            int d = d0 + c, hh = d >> 6, dd = d & 63;
            size_t dst = ((size_t)(b * 16 + hh) * 64 + dd) * 2048 + s_base + r;
            *(uint4*)(vtb + dst) = *(const uint4*)&Cs[c][r];
        }
    } else {
#pragma unroll
        for (int im = 0; im < 4; ++im)
#pragma unroll
            for (int in = 0; in < 4; ++in)
#pragma unroll
                for (int rg = 0; rg < 4; ++rg)
                    Cs[wm + im * 16 + quad * 4 + rg][wn + in * 16 + cl] =
                        f2bf(acc[im][in][rg]);
        __syncthreads();
        unsigned short* outp = (chunk == 0) ? kb : qb;
#pragma unroll
        for (int it = 0; it < 8; ++it) {
            int l = it * 2048 + tid * 8;
            int r = l >> 7;               // s-offset
            int c = l & 127;              // d-index (multiple of 8)
            int d = d0 + c, hh = d >> 6, dd = d & 63;
            size_t dst = ((size_t)(b * 16 + hh) * 2048 + s_base + r) * 64 + dd;
            *(uint4*)(outp + dst) = *(const uint4*)&Cs[r][c];
        }
    }
}

// ---------------------------------------------------------------- fused attention
// v4: grid (32, 16, 2); block 256 = 4 waves x 16 q-rows (64-row q-tile).
// T3-lite pipeline: K and V DOUBLE-BUFFERED in LDS; the loop-top barrier
// retires the prefetch issued one full compute-phase earlier, so the stage
// latency (the 2-barrier structure's serial stall, m233) hides under QK/exp/PV.
// One barrier per tile-step. LDS = Kt2(16K)+Vt2(16K)+Ps(8K) = 40960 B exactly
// -> 4 blocks/CU, 16 waves/CU at the (256,4) 128-VGPR cap.
// Ps at stride 64 is XOR-chunk-swizzled (both sides) to stay conflict-free.
__global__ __launch_bounds__(256, 4) void attn_kernel(
    const unsigned short* __restrict__ qb,   // [B,H,S,64]
    const unsigned short* __restrict__ kb,   // [B,H,S,64]
    const unsigned short* __restrict__ vtb,  // [B,H,64,S]
    float* __restrict__ out_,                // [B,S,1024]
    float* __restrict__ attn) {              // [B,H,S,S]
    const int h = blockIdx.y;
    const int b = blockIdx.z;
    const int bh = b * 16 + h;
    const int t64 = (23 * (int)blockIdx.x + 7 * bh) & 31;   // 64-row tile idx
    const int tid = threadIdx.x;
    const int w = tid >> 6;
    const int lane = tid & 63;
    const int quad = lane >> 4;
    const int cl = lane & 15;
    const int q0 = t64 * 64;
    const int row0 = q0 + w * 16;
    const int jtmax = t64;                   // uniform across the block

    const unsigned short* Qh = qb + (size_t)bh * 2048 * 64;
    const unsigned short* Kh = kb + (size_t)bh * 2048 * 64;
    const unsigned short* Vh = vtb + (size_t)bh * 64 * 2048;
    float* attnh = attn + (size_t)bh * 2048 * 2048;

    __shared__ __attribute__((aligned(16))) unsigned short Kt[2][64][64];  // 16 KB
    __shared__ __attribute__((aligned(16))) unsigned short Vt[2][64][64];  // 16 KB
    __shared__ __attribute__((aligned(16))) unsigned short Ps[4][16][64];  //  8 KB

    // staging lane mapping (identical to gemm): 8 rows x 128B per instr,
    // source chunk pre-XORed so LDS slot s of row r holds chunk s^(r&7).
    const int srow = lane >> 3;
    const int schk = (lane & 7) ^ srow;

    auto stageK = [&](int jt, int buf) {
#pragma unroll
        for (int i = 0; i < 2; ++i)
            gld_lds16(Kh + (size_t)(jt * 64 + w * 16 + i * 8 + srow) * 64 + schk * 8,
                      &Kt[buf][w * 16 + i * 8][0]);
    };
    auto stageV = [&](int j0, int buf) {
#pragma unroll
        for (int i = 0; i < 2; ++i)
            gld_lds16(Vh + (size_t)(w * 16 + i * 8 + srow) * 2048 + j0 + schk * 8,
                      &Vt[buf][w * 16 + i * 8][0]);
    };

    // Q fragments (A-operand): lane holds Q[row0+cl][kc*32 + quad*8 + j]
    short8 aq0 = *(const short8*)(Qh + (size_t)(row0 + cl) * 64 + quad * 8);
    short8 aq1 = *(const short8*)(Qh + (size_t)(row0 + cl) * 64 + 32 + quad * 8);

    const float mh = exp2f(-0.5f * (float)(h + 1));  // ALiBi slope 2^-((h+1)/2)
    const float sc1 = 1.0f / 32.0f;                  // 1/sqrt(1024)

    // ---- trip 1: row sums of exp(score) (max-free: |score| is O(1))
    float rsum[4] = {0.f, 0.f, 0.f, 0.f};
    stageK(0, 0);
    {
        int cur = 0;
        for (int jt = 0; jt <= jtmax; ++jt, cur ^= 1) {
            __syncthreads();                 // retires prefetch issued last phase
            if (jt < jtmax) stageK(jt + 1, cur ^ 1);   // fly during compute
            const int j0 = jt * 64;
#pragma unroll
            for (int nt = 0; nt < 4; ++nt) {
                const int r = nt * 16 + cl;
                short8 k0 = *(const short8*)&Kt[cur][r][((quad) ^ (cl & 7)) * 8];
                short8 k1 = *(const short8*)&Kt[cur][r][((quad + 4) ^ (cl & 7)) * 8];
                f32x4 s = {0.f, 0.f, 0.f, 0.f};
                s = __builtin_amdgcn_mfma_f32_16x16x32_bf16(aq0, k0, s, 0, 0, 0);
                s = __builtin_amdgcn_mfma_f32_16x16x32_bf16(aq1, k1, s, 0, 0, 0);
                const int jc = j0 + nt * 16 + cl;
#pragma unroll
                for (int rg = 0; rg < 4; ++rg) {
                    int irow = row0 + quad * 4 + rg;
                    if (jc <= irow)
                        rsum[rg] += __expf(s[rg] * sc1 + mh * (float)(jc - irow));
                }
            }
        }
    }
#pragma unroll
    for (int rg = 0; rg < 4; ++rg) {
        float v = rsum[rg];
        v += __shfl_xor(v, 1);
        v += __shfl_xor(v, 2);
        v += __shfl_xor(v, 4);
        v += __shfl_xor(v, 8);
        rsum[rg] = 1.0f / v;   // inv row-sum, valid on every lane of the quad
    }

    // ---- trip 2: recompute, normalize, emit attn, accumulate O = P @ V
    __syncthreads();           // all trip-1 reads done before restaging buf 0
    f32x4 oacc[4] = {};
    stageK(0, 0);
    stageV(0, 0);
    {
        int cur = 0;
        for (int jt = 0; jt <= jtmax; ++jt, cur ^= 1) {
            __syncthreads();                 // retires prefetch issued last phase
            if (jt < jtmax) {
                stageK(jt + 1, cur ^ 1);
                stageV(jt * 64 + 64, cur ^ 1);
            }
            const int j0 = jt * 64;
            f32x4 sv[4];
#pragma unroll
            for (int nt = 0; nt < 4; ++nt) {
                const int r = nt * 16 + cl;
                short8 k0 = *(const short8*)&Kt[cur][r][((quad) ^ (cl & 7)) * 8];
                short8 k1 = *(const short8*)&Kt[cur][r][((quad + 4) ^ (cl & 7)) * 8];
                f32x4 s = {0.f, 0.f, 0.f, 0.f};
                s = __builtin_amdgcn_mfma_f32_16x16x32_bf16(aq0, k0, s, 0, 0, 0);
                sv[nt] = __builtin_amdgcn_mfma_f32_16x16x32_bf16(aq1, k1, s, 0, 0, 0);
            }
#pragma unroll
            for (int nt = 0; nt < 4; ++nt) {
                const int jc = j0 + nt * 16 + cl;
#pragma unroll
                for (int rg = 0; rg < 4; ++rg) {
                    const int irow = row0 + quad * 4 + rg;
                    float p = (jc <= irow)
                                  ? __expf(sv[nt][rg] * sc1 + mh * (float)(jc - irow)) * rsum[rg]
                                  : 0.f;
                    // Ps chunk-XOR swizzle: logical col nt*16+cl, row quad*4+rg;
                    // chunk (nt*2 + cl/8) stored at chunk^(row&7).
                    Ps[w][quad * 4 + rg]
                      [(((nt * 2 + (cl >> 3)) ^ ((quad * 4 + rg) & 7)) << 3) | (cl & 7)] =
                        f2bf(p);
                    // attn store from C-layout: 16 cl-lanes of each quad cover
                    // one FULL 64B segment (4 rows per instruction).
                    __builtin_nontemporal_store(p, attnh + (size_t)irow * 2048 + jc);
                }
            }

            // P strip: A-operand fragments (lane = row cl, k contiguous);
            // logical chunk quad (pa0) / 4+quad (pa1) stored at chunk^(cl&7).
            short8 pa0 = *(const short8*)&Ps[w][cl][((quad ^ (cl & 7)) << 3)];
            short8 pa1 = *(const short8*)&Ps[w][cl][((((quad + 4)) ^ (cl & 7)) << 3)];

            // O += P @ V   (B-frag: row of Vt = d-index, cols = k; swizzled read)
#pragma unroll
            for (int on = 0; on < 4; ++on) {
                const int r = on * 16 + cl;
                short8 v0 = *(const short8*)&Vt[cur][r][((quad) ^ (cl & 7)) * 8];
                short8 v1 = *(const short8*)&Vt[cur][r][((quad + 4) ^ (cl & 7)) * 8];
                oacc[on] = __builtin_amdgcn_mfma_f32_16x16x32_bf16(pa0, v0, oacc[on], 0, 0, 0);
                oacc[on] = __builtin_amdgcn_mfma_f32_16x16x32_bf16(pa1, v1, oacc[on], 0, 0, 0);
            }
        }
    }

    // O epilogue: out[b, s, h*64 + d]  (quad covers a 64B contiguous segment)
#pragma unroll
    for (int on = 0; on < 4; ++on) {
#pragma unroll
        for (int rg = 0; rg < 4; ++rg) {
            int srow2 = row0 + quad * 4 + rg;
            __builtin_nontemporal_store(
                oacc[on][rg], out_ + ((size_t)b * 2048 + srow2) * 1024 + h * 64 + on * 16 + cl);
        }
    }

    // zero-fill strictly-future columns (d_out is poisoned, zeros must be written)
    const int jz = (jtmax + 1) * 64;
    if (jz < 2048) {
        f32x4 z = {0.f, 0.f, 0.f, 0.f};
        for (int rr = 0; rr < 16; ++rr) {
            float* dst = attnh + (size_t)(row0 + rr) * 2048;
            for (int c = jz + lane * 4; c < 2048; c += 256)
                __builtin_nontemporal_store(z, (f32x4*)(dst + c));
        }
    }
}

// ---------------------------------------------------------------- launch
extern "C" void kernel_launch(void* const* d_in, const int* in_sizes, int n_in,
                              void* d_out, int out_size, void* d_ws, size_t ws_size,
                              hipStream_t stream) {
    const float* x = (const float*)d_in[0];     // [2,2048,1024]
    const float* Wk = (const float*)d_in[1];    // [1024,3072]
    float* out = (float*)d_out;                 // [2,2048,1024] fp32
    float* attn = out + (size_t)2 * 2048 * 1024;  // [2,16,2048,2048] fp32

    unsigned short* xb = (unsigned short*)d_ws;                 // 8 MB
    unsigned short* wtb = xb + (size_t)4096 * 1024;             // 6 MB
    unsigned short* qb = wtb + (size_t)3072 * 1024;             // 8 MB
    unsigned short* kb = qb + (size_t)32 * 2048 * 64;           // 8 MB
    unsigned short* vtb = kb + (size_t)32 * 2048 * 64;          // 8 MB

    cvt_x_kernel<<<dim3(4096), dim3(256), 0, stream>>>(x, xb, 4096 * 1024 / 4);
    cvt_wt_kernel<<<dim3(48, 16), dim3(256), 0, stream>>>(Wk, wtb);
    gemm_kqv_kernel<<<dim3(24, 32), dim3(256), 0, stream>>>(xb, wtb, qb, kb, vtb);
    attn_kernel<<<dim3(32, 16, 2), dim3(256), 0, stream>>>(qb, kb, vtb, out, attn);
}

// Round 5
// 692.425 us; speedup vs baseline: 1.2639x; 1.0121x over previous
//
#include <hip/hip_runtime.h>
#include <hip/hip_bf16.h>

typedef __attribute__((ext_vector_type(8))) short short8;
typedef __attribute__((ext_vector_type(4))) float f32x4;

// fp32 -> bf16 RNE
static __device__ __forceinline__ unsigned short f2bf(float f) {
    unsigned int x = __float_as_uint(f);
    x += 0x7fffu + ((x >> 16) & 1u);
    return (unsigned short)(x >> 16);
}

// async global->LDS, 16B per lane. LDS dest = wave-uniform base + lane*16.
static __device__ __forceinline__ void gld_lds16(const unsigned short* g, unsigned short* l) {
    __builtin_amdgcn_global_load_lds((const __attribute__((address_space(1))) void*)g,
                                     (__attribute__((address_space(3))) void*)l, 16, 0, 0);
}

// ---------------------------------------------------------------- converts
__global__ __launch_bounds__(256) void cvt_x_kernel(const float* __restrict__ in,
                                                    unsigned short* __restrict__ outb,
                                                    int n4) {
    int i = blockIdx.x * 256 + threadIdx.x;
    if (i < n4) {
        f32x4 v = *(const f32x4*)(in + (size_t)i * 4);
        ushort4 o;
        o.x = f2bf(v[0]); o.y = f2bf(v[1]); o.z = f2bf(v[2]); o.w = f2bf(v[3]);
        *(ushort4*)(outb + (size_t)i * 4) = o;
    }
}

// W [1024 x 3072] fp32  ->  WT [3072 x 1024] bf16   (tiled LDS transpose)
__global__ __launch_bounds__(256) void cvt_wt_kernel(const float* __restrict__ W,
                                                     unsigned short* __restrict__ WT) {
    __shared__ float t[64][65];
    const int n0 = blockIdx.x * 64;   // 48
    const int k0 = blockIdx.y * 64;   // 16
    const int tid = threadIdx.x;
#pragma unroll
    for (int i = 0; i < 16; ++i) {
        int lin = tid + i * 256;
        int rr = lin >> 6, cc = lin & 63;
        t[rr][cc] = W[(size_t)(k0 + rr) * 3072 + n0 + cc];
    }
    __syncthreads();
#pragma unroll
    for (int i = 0; i < 16; ++i) {
        int lin = tid + i * 256;
        int nn = lin >> 6, kk = lin & 63;
        WT[(size_t)(n0 + nn) * 1024 + k0 + kk] = f2bf(t[kk][nn]);
    }
}

// ---------------------------------------------------------------- GEMM
// C[4096,3072] = A[4096,1024] @ W[1024,3072], operands [rows,K] bf16.
// m97 structure: global_load_lds width=16 into LINEAR [128][64] LDS tiles.
// Bank-conflict fix (rule 21, both-sides): LDS stays linear; the GLOBAL
// source is chunk-permuted (chunk ^= row&7, row&7 == lane>>3 here), and the
// ds_read column applies the matching XOR -> 16-way conflict becomes 2-way.
// Bijective XCD swizzle on the 768-block grid (768 % 8 == 0).
__global__ __launch_bounds__(256) void gemm_kqv_kernel(
    const unsigned short* __restrict__ A,   // xb  [4096,1024]
    const unsigned short* __restrict__ BT,  // WTb [3072,1024]
    unsigned short* __restrict__ qb,
    unsigned short* __restrict__ kb,
    unsigned short* __restrict__ vtb) {
    __shared__ __attribute__((aligned(16))) unsigned short smem[2 * 128 * 72];  // 36864 B
    unsigned short (*As)[64] = (unsigned short(*)[64])smem;             // 16 KB
    unsigned short (*Bs)[64] = (unsigned short(*)[64])(smem + 128 * 64);
    const int tid = threadIdx.x;
    const int w = tid >> 6, lane = tid & 63;
    const int quad = lane >> 4, cl = lane & 15;

    // XCD-aware bijective swizzle: 8 XCDs x 96 contiguous tiles each
    const int wg = (int)blockIdx.x + 24 * (int)blockIdx.y;   // 0..767
    const int wgs = (wg & 7) * 96 + (wg >> 3);
    const int m0 = (wgs / 24) * 128, n0 = (wgs % 24) * 128;
    const int wm = (w >> 1) * 64, wn = (w & 1) * 64;

    // staging: wave w covers rows [w*32, w*32+32), 8 rows / instr.
    // global chunk pre-swizzled: chunk = (lane&7) ^ (lane>>3)  (row&7 == lane>>3)
    const int srow = lane >> 3;
    const int schk = (lane & 7) ^ srow;
    const unsigned short* Ap = A + (size_t)(m0 + w * 32 + srow) * 1024 + schk * 8;
    const unsigned short* Bp = BT + (size_t)(n0 + w * 32 + srow) * 1024 + schk * 8;

    f32x4 acc[4][4] = {};

    for (int kk = 0; kk < 1024; kk += 64) {
#pragma unroll
        for (int i = 0; i < 4; ++i) {
            gld_lds16(Ap + kk + (size_t)i * 8 * 1024, &As[w * 32 + i * 8][0]);
            gld_lds16(Bp + kk + (size_t)i * 8 * 1024, &Bs[w * 32 + i * 8][0]);
        }
        __syncthreads();   // drains vmcnt -> LDS tiles complete
#pragma unroll
        for (int kc = 0; kc < 2; ++kc) {
            short8 af[4], bfr[4];
#pragma unroll
            for (int i = 0; i < 4; ++i) {
                // logical chunk 4kc+quad of row (..+cl), stored at chunk^(cl&7)
                const int col = ((kc * 4 + quad) ^ (cl & 7)) * 8;
                af[i] = *(const short8*)&As[wm + i * 16 + cl][col];
                bfr[i] = *(const short8*)&Bs[wn + i * 16 + cl][col];
            }
#pragma unroll
            for (int im = 0; im < 4; ++im)
#pragma unroll
                for (int in = 0; in < 4; ++in)
                    acc[im][in] = __builtin_amdgcn_mfma_f32_16x16x32_bf16(
                        af[im], bfr[in], acc[im][in], 0, 0, 0);
        }
        __syncthreads();
    }
    // k-loop ended with __syncthreads(): safe to reuse smem as C-tile staging.
    unsigned short (*Cs)[130] = (unsigned short(*)[130])smem;  // 33280 B <= 36864 B

    const int chunk = n0 >> 10;           // 0:k 1:q 2:v (jnp.split order)
    const int d0 = n0 & 1023;
    const int b = m0 >> 11;               // tile never crosses batch boundary
    const int s_base = m0 & 2047;

    if (chunk == 2) {
        // stage TRANSPOSED: Cs[d-idx][s-idx]
#pragma unroll
        for (int im = 0; im < 4; ++im)
#pragma unroll
            for (int in = 0; in < 4; ++in)
#pragma unroll
                for (int rg = 0; rg < 4; ++rg)
                    Cs[wn + in * 16 + cl][wm + im * 16 + quad * 4 + rg] =
                        f2bf(acc[im][in][rg]);
        __syncthreads();
#pragma unroll
        for (int it = 0; it < 8; ++it) {
            int l = it * 2048 + tid * 8;
            int c = l >> 7;               // d-index 0..127
            int r = l & 127;              // s-offset (multiple of 8)
            int d = d0 + c, hh = d >> 6, dd = d & 63;
            size_t dst = ((size_t)(b * 16 + hh) * 64 + dd) * 2048 + s_base + r;
            *(uint4*)(vtb + dst) = *(const uint4*)&Cs[c][r];
        }
    } else {
#pragma unroll
        for (int im = 0; im < 4; ++im)
#pragma unroll
            for (int in = 0; in < 4; ++in)
#pragma unroll
                for (int rg = 0; rg < 4; ++rg)
                    Cs[wm + im * 16 + quad * 4 + rg][wn + in * 16 + cl] =
                        f2bf(acc[im][in][rg]);
        __syncthreads();
        unsigned short* outp = (chunk == 0) ? kb : qb;
#pragma unroll
        for (int it = 0; it < 8; ++it) {
            int l = it * 2048 + tid * 8;
            int r = l >> 7;               // s-offset
            int c = l & 127;              // d-index (multiple of 8)
            int d = d0 + c, hh = d >> 6, dd = d & 63;
            size_t dst = ((size_t)(b * 16 + hh) * 2048 + s_base + r) * 64 + dd;
            *(uint4*)(outp + dst) = *(const uint4*)&Cs[r][c];
        }
    }
}

// ---------------------------------------------------------------- fused attention
// v5: UNIFORM-WORK PAIRING. grid (16, 16, 2) = 512 blocks, 4 waves each.
// Block bx processes q-tile bx then q-tile 31-bx sequentially: total work
// = 2*((bx+1) + (32-bx)) = 66 tile-steps for EVERY block -> no ragged tail.
// (v4's 1024 all-resident blocks had a 32:1 work spread with zero backfill;
// kernel time degraded into an idle-machine tail of heavy blocks.)
// K/V double-buffered in LDS (one barrier per tile-step), XOR-chunk swizzle
// both-sides on Kt/Vt/Ps. LDS 40 KB; __launch_bounds__(256,2) -> no VGPR cap
// pressure (2 blocks/CU is all we need for 512 blocks on 256 CUs).
__global__ __launch_bounds__(256, 2) void attn_kernel(
    const unsigned short* __restrict__ qb,   // [B,H,S,64]
    const unsigned short* __restrict__ kb,   // [B,H,S,64]
    const unsigned short* __restrict__ vtb,  // [B,H,64,S]
    float* __restrict__ out_,                // [B,S,1024]
    float* __restrict__ attn) {              // [B,H,S,S]
    const int h = blockIdx.y;
    const int b = blockIdx.z;
    const int bh = b * 16 + h;
    const int tid = threadIdx.x;
    const int w = tid >> 6;
    const int lane = tid & 63;
    const int quad = lane >> 4;
    const int cl = lane & 15;

    const unsigned short* Qh = qb + (size_t)bh * 2048 * 64;
    const unsigned short* Kh = kb + (size_t)bh * 2048 * 64;
    const unsigned short* Vh = vtb + (size_t)bh * 64 * 2048;
    float* attnh = attn + (size_t)bh * 2048 * 2048;

    __shared__ __attribute__((aligned(16))) unsigned short Kt[2][64][64];  // 16 KB
    __shared__ __attribute__((aligned(16))) unsigned short Vt[2][64][64];  // 16 KB
    __shared__ __attribute__((aligned(16))) unsigned short Ps[4][16][64];  //  8 KB

    // staging lane mapping (identical to gemm): 8 rows x 128B per instr,
    // source chunk pre-XORed so LDS slot s of row r holds chunk s^(r&7).
    const int srow = lane >> 3;
    const int schk = (lane & 7) ^ srow;

    auto stageK = [&](int jt, int buf) {
#pragma unroll
        for (int i = 0; i < 2; ++i)
            gld_lds16(Kh + (size_t)(jt * 64 + w * 16 + i * 8 + srow) * 64 + schk * 8,
                      &Kt[buf][w * 16 + i * 8][0]);
    };
    auto stageV = [&](int j0, int buf) {
#pragma unroll
        for (int i = 0; i < 2; ++i)
            gld_lds16(Vh + (size_t)(w * 16 + i * 8 + srow) * 2048 + j0 + schk * 8,
                      &Vt[buf][w * 16 + i * 8][0]);
    };

    const float mh = exp2f(-0.5f * (float)(h + 1));  // ALiBi slope 2^-((h+1)/2)
    const float sc1 = 1.0f / 32.0f;                  // 1/sqrt(1024)

    for (int half = 0; half < 2; ++half) {
        const int t64 = half ? 31 - (int)blockIdx.x : (int)blockIdx.x;
        const int q0 = t64 * 64;
        const int row0 = q0 + w * 16;
        const int jtmax = t64;               // uniform across the block

        // Q fragments (A-operand): lane holds Q[row0+cl][kc*32 + quad*8 + j]
        short8 aq0 = *(const short8*)(Qh + (size_t)(row0 + cl) * 64 + quad * 8);
        short8 aq1 = *(const short8*)(Qh + (size_t)(row0 + cl) * 64 + 32 + quad * 8);

        // ---- trip 1: row sums of exp(score) (max-free: |score| is O(1))
        float rsum[4] = {0.f, 0.f, 0.f, 0.f};
        __syncthreads();                     // prior half's LDS reads complete
        stageK(0, 0);
        {
            int cur = 0;
            for (int jt = 0; jt <= jtmax; ++jt, cur ^= 1) {
                __syncthreads();             // retires prefetch issued last phase
                if (jt < jtmax) stageK(jt + 1, cur ^ 1);   // fly during compute
                const int j0 = jt * 64;
#pragma unroll
                for (int nt = 0; nt < 4; ++nt) {
                    const int r = nt * 16 + cl;
                    short8 k0 = *(const short8*)&Kt[cur][r][((quad) ^ (cl & 7)) * 8];
                    short8 k1 = *(const short8*)&Kt[cur][r][((quad + 4) ^ (cl & 7)) * 8];
                    f32x4 s = {0.f, 0.f, 0.f, 0.f};
                    s = __builtin_amdgcn_mfma_f32_16x16x32_bf16(aq0, k0, s, 0, 0, 0);
                    s = __builtin_amdgcn_mfma_f32_16x16x32_bf16(aq1, k1, s, 0, 0, 0);
                    const int jc = j0 + nt * 16 + cl;
#pragma unroll
                    for (int rg = 0; rg < 4; ++rg) {
                        int irow = row0 + quad * 4 + rg;
                        if (jc <= irow)
                            rsum[rg] += __expf(s[rg] * sc1 + mh * (float)(jc - irow));
                    }
                }
            }
        }
#pragma unroll
        for (int rg = 0; rg < 4; ++rg) {
            float v = rsum[rg];
            v += __shfl_xor(v, 1);
            v += __shfl_xor(v, 2);
            v += __shfl_xor(v, 4);
            v += __shfl_xor(v, 8);
            rsum[rg] = 1.0f / v;   // inv row-sum, valid on every lane of the quad
        }

        // ---- trip 2: recompute, normalize, emit attn, accumulate O = P @ V
        __syncthreads();           // all trip-1 reads done before restaging buf 0
        f32x4 oacc[4] = {};
        stageK(0, 0);
        stageV(0, 0);
        {
            int cur = 0;
            for (int jt = 0; jt <= jtmax; ++jt, cur ^= 1) {
                __syncthreads();             // retires prefetch issued last phase
                if (jt < jtmax) {
                    stageK(jt + 1, cur ^ 1);
                    stageV(jt * 64 + 64, cur ^ 1);
                }
                const int j0 = jt * 64;
                f32x4 sv[4];
#pragma unroll
                for (int nt = 0; nt < 4; ++nt) {
                    const int r = nt * 16 + cl;
                    short8 k0 = *(const short8*)&Kt[cur][r][((quad) ^ (cl & 7)) * 8];
                    short8 k1 = *(const short8*)&Kt[cur][r][((quad + 4) ^ (cl & 7)) * 8];
                    f32x4 s = {0.f, 0.f, 0.f, 0.f};
                    s = __builtin_amdgcn_mfma_f32_16x16x32_bf16(aq0, k0, s, 0, 0, 0);
                    sv[nt] = __builtin_amdgcn_mfma_f32_16x16x32_bf16(aq1, k1, s, 0, 0, 0);
                }
#pragma unroll
                for (int nt = 0; nt < 4; ++nt) {
                    const int jc = j0 + nt * 16 + cl;
#pragma unroll
                    for (int rg = 0; rg < 4; ++rg) {
                        const int irow = row0 + quad * 4 + rg;
                        float p = (jc <= irow)
                                      ? __expf(sv[nt][rg] * sc1 + mh * (float)(jc - irow)) * rsum[rg]
                                      : 0.f;
                        // Ps chunk-XOR swizzle: logical col nt*16+cl, row quad*4+rg;
                        // chunk (nt*2 + cl/8) stored at chunk^(row&7).
                        Ps[w][quad * 4 + rg]
                          [(((nt * 2 + (cl >> 3)) ^ ((quad * 4 + rg) & 7)) << 3) | (cl & 7)] =
                            f2bf(p);
                        // attn store from C-layout: 16 cl-lanes of each quad cover
                        // one FULL 64B segment (4 rows per instruction).
                        __builtin_nontemporal_store(p, attnh + (size_t)irow * 2048 + jc);
                    }
                }

                // P strip: A-operand fragments (lane = row cl, k contiguous);
                // logical chunk quad (pa0) / 4+quad (pa1) stored at chunk^(cl&7).
                short8 pa0 = *(const short8*)&Ps[w][cl][((quad ^ (cl & 7)) << 3)];
                short8 pa1 = *(const short8*)&Ps[w][cl][((((quad + 4)) ^ (cl & 7)) << 3)];

                // O += P @ V   (B-frag: row of Vt = d-index, cols = k; swizzled read)
#pragma unroll
                for (int on = 0; on < 4; ++on) {
                    const int r = on * 16 + cl;
                    short8 v0 = *(const short8*)&Vt[cur][r][((quad) ^ (cl & 7)) * 8];
                    short8 v1 = *(const short8*)&Vt[cur][r][((quad + 4) ^ (cl & 7)) * 8];
                    oacc[on] = __builtin_amdgcn_mfma_f32_16x16x32_bf16(pa0, v0, oacc[on], 0, 0, 0);
                    oacc[on] = __builtin_amdgcn_mfma_f32_16x16x32_bf16(pa1, v1, oacc[on], 0, 0, 0);
                }
            }
        }

        // O epilogue: out[b, s, h*64 + d]  (quad covers a 64B contiguous segment)
#pragma unroll
        for (int on = 0; on < 4; ++on) {
#pragma unroll
            for (int rg = 0; rg < 4; ++rg) {
                int srow2 = row0 + quad * 4 + rg;
                __builtin_nontemporal_store(
                    oacc[on][rg], out_ + ((size_t)b * 2048 + srow2) * 1024 + h * 64 + on * 16 + cl);
            }
        }

        // zero-fill strictly-future columns (d_out poisoned, zeros must be written)
        const int jz = (jtmax + 1) * 64;
        if (jz < 2048) {
            f32x4 z = {0.f, 0.f, 0.f, 0.f};
            for (int rr = 0; rr < 16; ++rr) {
                float* dst = attnh + (size_t)(row0 + rr) * 2048;
                for (int c = jz + lane * 4; c < 2048; c += 256)
                    __builtin_nontemporal_store(z, (f32x4*)(dst + c));
            }
        }
    }
}

// ---------------------------------------------------------------- launch
extern "C" void kernel_launch(void* const* d_in, const int* in_sizes, int n_in,
                              void* d_out, int out_size, void* d_ws, size_t ws_size,
                              hipStream_t stream) {
    const float* x = (const float*)d_in[0];     // [2,2048,1024]
    const float* Wk = (const float*)d_in[1];    // [1024,3072]
    float* out = (float*)d_out;                 // [2,2048,1024] fp32
    float* attn = out + (size_t)2 * 2048 * 1024;  // [2,16,2048,2048] fp32

    unsigned short* xb = (unsigned short*)d_ws;                 // 8 MB
    unsigned short* wtb = xb + (size_t)4096 * 1024;             // 6 MB
    unsigned short* qb = wtb + (size_t)3072 * 1024;             // 8 MB
    unsigned short* kb = qb + (size_t)32 * 2048 * 64;           // 8 MB
    unsigned short* vtb = kb + (size_t)32 * 2048 * 64;          // 8 MB

    cvt_x_kernel<<<dim3(4096), dim3(256), 0, stream>>>(x, xb, 4096 * 1024 / 4);
    cvt_wt_kernel<<<dim3(48, 16), dim3(256), 0, stream>>>(Wk, wtb);
    gemm_kqv_kernel<<<dim3(24, 32), dim3(256), 0, stream>>>(xb, wtb, qb, kb, vtb);
    attn_kernel<<<dim3(16, 16, 2), dim3(256), 0, stream>>>(qb, kb, vtb, out, attn);
}

// Round 6
// 686.965 us; speedup vs baseline: 1.2740x; 1.0079x over previous
//
#include <hip/hip_runtime.h>
#include <hip/hip_bf16.h>

typedef __attribute__((ext_vector_type(8))) short short8;
typedef __attribute__((ext_vector_type(4))) float f32x4;

// fp32 -> bf16 RNE
static __device__ __forceinline__ unsigned short f2bf(float f) {
    unsigned int x = __float_as_uint(f);
    x += 0x7fffu + ((x >> 16) & 1u);
    return (unsigned short)(x >> 16);
}

// async global->LDS, 16B per lane. LDS dest = wave-uniform base + lane*16.
static __device__ __forceinline__ void gld_lds16(const unsigned short* g, unsigned short* l) {
    __builtin_amdgcn_global_load_lds((const __attribute__((address_space(1))) void*)g,
                                     (__attribute__((address_space(3))) void*)l, 16, 0, 0);
}

// ---------------------------------------------------------------- converts
__global__ __launch_bounds__(256) void cvt_x_kernel(const float* __restrict__ in,
                                                    unsigned short* __restrict__ outb,
                                                    int n4) {
    int i = blockIdx.x * 256 + threadIdx.x;
    if (i < n4) {
        f32x4 v = *(const f32x4*)(in + (size_t)i * 4);
        ushort4 o;
        o.x = f2bf(v[0]); o.y = f2bf(v[1]); o.z = f2bf(v[2]); o.w = f2bf(v[3]);
        *(ushort4*)(outb + (size_t)i * 4) = o;
    }
}

// W [1024 x 3072] fp32  ->  WT [3072 x 1024] bf16   (tiled LDS transpose)
__global__ __launch_bounds__(256) void cvt_wt_kernel(const float* __restrict__ W,
                                                     unsigned short* __restrict__ WT) {
    __shared__ float t[64][65];
    const int n0 = blockIdx.x * 64;   // 48
    const int k0 = blockIdx.y * 64;   // 16
    const int tid = threadIdx.x;
#pragma unroll
    for (int i = 0; i < 16; ++i) {
        int lin = tid + i * 256;
        int rr = lin >> 6, cc = lin & 63;
        t[rr][cc] = W[(size_t)(k0 + rr) * 3072 + n0 + cc];
    }
    __syncthreads();
#pragma unroll
    for (int i = 0; i < 16; ++i) {
        int lin = tid + i * 256;
        int nn = lin >> 6, kk = lin & 63;
        WT[(size_t)(n0 + nn) * 1024 + k0 + kk] = f2bf(t[kk][nn]);
    }
}

// ---------------------------------------------------------------- GEMM (8-phase-style 256^2)
// C[4096,3072] = A[4096,1024] @ W[1024,3072], operands [rows,K] bf16.
// 256x256 tile, BK=64, 512 thr = 8 waves (2M x 4N), per-wave C = 128x64.
// LDS: 2 x (A 256x64 + B 256x64) bf16 = 128 KB, double-buffered.
// K-loop: 4 phases/tile; phase = {issue 1/4 of NEXT tile's global_load_lds,
// ds_read quadrant frags, setprio(1), 16 MFMA, setprio(0), RAW s_barrier}.
// No __syncthreads() in the loop (it drains vmcnt(0) = the 2-phase stall);
// tile entry waits inline-asm vmcnt(0) on loads issued a FULL TILE earlier
// (~3 phases of compute in flight -> wait is ~free; A/B are L2-resident).
// Both-sides XOR chunk swizzle (conflict-free ds_read_b128). XCD swizzle
// (192 blocks % 8 == 0): consecutive wgs on an XCD share the A panel.
__global__ __launch_bounds__(512, 2) void gemm_kqv_kernel(
    const unsigned short* __restrict__ A,   // xb  [4096,1024]
    const unsigned short* __restrict__ BT,  // WTb [3072,1024]
    unsigned short* __restrict__ qb,
    unsigned short* __restrict__ kb,
    unsigned short* __restrict__ vtb) {
    __shared__ __attribute__((aligned(16))) unsigned short smem[2 * 2 * 256 * 64];  // 128 KB
    unsigned short (*As)[256][64] = (unsigned short(*)[256][64])smem;
    unsigned short (*Bs)[256][64] = (unsigned short(*)[256][64])(smem + 2 * 256 * 64);
    const int tid = threadIdx.x;
    const int w = tid >> 6, lane = tid & 63;
    const int quad = lane >> 4, cl = lane & 15;

    // XCD-aware bijective swizzle: 8 XCDs x 24 contiguous tiles (192 % 8 == 0).
    // wgs/12 = m-tile, wgs%12 = n-tile -> per-XCD run shares 2 m-panels.
    const int wg = (int)blockIdx.x + 12 * (int)blockIdx.y;   // 0..191
    const int wgs = (wg & 7) * 24 + (wg >> 3);
    const int m0 = (wgs / 12) * 256, n0 = (wgs % 12) * 256;
    const int wm = (w >> 2) * 128, wn = (w & 3) * 64;

    // staging: call i covers rows [i*64, i*64+64) (wave w does +w*8, 8 rows).
    // global chunk pre-swizzled: slot s of row r holds chunk s^(r&7).
    const int srow = lane >> 3;
    const int schk = (lane & 7) ^ srow;
    const unsigned short* Ap = A + (size_t)(m0 + w * 8 + srow) * 1024 + schk * 8;
    const unsigned short* Bp = BT + (size_t)(n0 + w * 8 + srow) * 1024 + schk * 8;

    f32x4 acc[8][4] = {};

    auto stageA = [&](int kk, int buf) {
#pragma unroll
        for (int i = 0; i < 4; ++i)
            gld_lds16(Ap + kk + (size_t)i * 64 * 1024, &As[buf][i * 64 + w * 8][0]);
    };
    auto stageB = [&](int kk, int buf) {
#pragma unroll
        for (int i = 0; i < 4; ++i)
            gld_lds16(Bp + kk + (size_t)i * 64 * 1024, &Bs[buf][i * 64 + w * 8][0]);
    };

    stageA(0, 0);
    stageB(0, 0);

    for (int kt = 0; kt < 16; ++kt) {
        const int cur = kt & 1;
        // tile kt's 8 loads were issued during kt-1 (>= 3 phases ago)
        asm volatile("s_waitcnt vmcnt(0)" ::: "memory");
        __builtin_amdgcn_s_barrier();

        // B fragments for the whole tile (live across the 4 phases)
        short8 bfr[4][2];
#pragma unroll
        for (int n = 0; n < 4; ++n)
#pragma unroll
            for (int kc = 0; kc < 2; ++kc)
                bfr[n][kc] = *(const short8*)
                    &Bs[cur][wn + n * 16 + cl][((kc * 4 + quad) ^ (cl & 7)) * 8];

#pragma unroll
        for (int q = 0; q < 4; ++q) {
            if (q == 0 && kt < 15) stageA(kt * 64 + 64, cur ^ 1);
            if (q == 1 && kt < 15) stageB(kt * 64 + 64, cur ^ 1);
            short8 af[2][2];
#pragma unroll
            for (int i = 0; i < 2; ++i)
#pragma unroll
                for (int kc = 0; kc < 2; ++kc)
                    af[i][kc] = *(const short8*)
                        &As[cur][wm + q * 32 + i * 16 + cl][((kc * 4 + quad) ^ (cl & 7)) * 8];
            __builtin_amdgcn_s_setprio(1);
#pragma unroll
            for (int i = 0; i < 2; ++i)
#pragma unroll
                for (int n = 0; n < 4; ++n)
#pragma unroll
                    for (int kc = 0; kc < 2; ++kc)
                        acc[q * 2 + i][n] = __builtin_amdgcn_mfma_f32_16x16x32_bf16(
                            af[i][kc], bfr[n][kc], acc[q * 2 + i][n], 0, 0, 0);
            __builtin_amdgcn_s_setprio(0);
            __builtin_amdgcn_sched_barrier(0);
            __builtin_amdgcn_s_barrier();   // raw: does NOT drain vmcnt
        }
    }

    // ---- epilogue (all LDS reads complete past the final barrier)
    const int chunk = n0 >> 10;           // 0:k 1:q 2:v (jnp.split order)
    const int d0 = n0 & 1023;
    const int b = m0 >> 11;               // 256-tile never crosses batch boundary
    const int s_base = m0 & 2047;

    if (chunk == 2) {
        // stage TRANSPOSED via LDS: Cs[d 0..255][s 0..255] (exactly 128 KB),
        // s-chunk XOR-swizzled by (d&7) -> bank-spread writes and reads.
        unsigned short (*Cs)[256] = (unsigned short(*)[256])smem;
        __syncthreads();                  // no DMA outstanding; safe full sync
#pragma unroll
        for (int im = 0; im < 8; ++im)
#pragma unroll
            for (int in = 0; in < 4; ++in)
#pragma unroll
                for (int rg = 0; rg < 4; ++rg) {
                    int dl = wn + in * 16 + cl;             // 0..255
                    int s = wm + im * 16 + quad * 4 + rg;   // 0..255
                    Cs[dl][(((s >> 3) ^ (dl & 7)) << 3) | (s & 7)] =
                        f2bf(acc[im][in][rg]);
                }
        __syncthreads();
#pragma unroll
        for (int it = 0; it < 16; ++it) {
            int l = it * 4096 + tid * 8;
            int dr = l >> 8;              // d-index 0..255
            int r = l & 255;              // s-offset (multiple of 8)
            int d = d0 + dr, hh = d >> 6, dd = d & 63;
            size_t dst = ((size_t)(b * 16 + hh) * 64 + dd) * 2048 + s_base + r;
            *(uint4*)(vtb + dst) = *(const uint4*)&Cs[dr][(((r >> 3) ^ (dr & 7)) << 3)];
        }
    } else {
        // k/q: direct stores from acc; each quad's 16 cl-lanes cover a 32B
        // contiguous d-segment (within one head: d0,wn,in*16 all mult of 16).
        unsigned short* outp = (chunk == 0) ? kb : qb;
#pragma unroll
        for (int im = 0; im < 8; ++im)
#pragma unroll
            for (int in = 0; in < 4; ++in)
#pragma unroll
                for (int rg = 0; rg < 4; ++rg) {
                    int s = s_base + wm + im * 16 + quad * 4 + rg;
                    int d = d0 + wn + in * 16 + cl;
                    int hh = d >> 6, dd = d & 63;
                    outp[((size_t)(b * 16 + hh) * 2048 + s) * 64 + dd] =
                        f2bf(acc[im][in][rg]);
                }
    }
}

// ---------------------------------------------------------------- fused attention
// v5 (unchanged from R5): UNIFORM-WORK PAIRING. grid (16, 16, 2) = 512 blocks.
// Block bx processes q-tile bx then q-tile 31-bx: 66 tile-steps per block.
// K/V double-buffered in LDS (one barrier per tile-step), XOR-chunk swizzle
// both-sides on Kt/Vt/Ps.
__global__ __launch_bounds__(256, 2) void attn_kernel(
    const unsigned short* __restrict__ qb,   // [B,H,S,64]
    const unsigned short* __restrict__ kb,   // [B,H,S,64]
    const unsigned short* __restrict__ vtb,  // [B,H,64,S]
    float* __restrict__ out_,                // [B,S,1024]
    float* __restrict__ attn) {              // [B,H,S,S]
    const int h = blockIdx.y;
    const int b = blockIdx.z;
    const int bh = b * 16 + h;
    const int tid = threadIdx.x;
    const int w = tid >> 6;
    const int lane = tid & 63;
    const int quad = lane >> 4;
    const int cl = lane & 15;

    const unsigned short* Qh = qb + (size_t)bh * 2048 * 64;
    const unsigned short* Kh = kb + (size_t)bh * 2048 * 64;
    const unsigned short* Vh = vtb + (size_t)bh * 64 * 2048;
    float* attnh = attn + (size_t)bh * 2048 * 2048;

    __shared__ __attribute__((aligned(16))) unsigned short Kt[2][64][64];  // 16 KB
    __shared__ __attribute__((aligned(16))) unsigned short Vt[2][64][64];  // 16 KB
    __shared__ __attribute__((aligned(16))) unsigned short Ps[4][16][64];  //  8 KB

    const int srow = lane >> 3;
    const int schk = (lane & 7) ^ srow;

    auto stageK = [&](int jt, int buf) {
#pragma unroll
        for (int i = 0; i < 2; ++i)
            gld_lds16(Kh + (size_t)(jt * 64 + w * 16 + i * 8 + srow) * 64 + schk * 8,
                      &Kt[buf][w * 16 + i * 8][0]);
    };
    auto stageV = [&](int j0, int buf) {
#pragma unroll
        for (int i = 0; i < 2; ++i)
            gld_lds16(Vh + (size_t)(w * 16 + i * 8 + srow) * 2048 + j0 + schk * 8,
                      &Vt[buf][w * 16 + i * 8][0]);
    };

    const float mh = exp2f(-0.5f * (float)(h + 1));  // ALiBi slope 2^-((h+1)/2)
    const float sc1 = 1.0f / 32.0f;                  // 1/sqrt(1024)

    for (int half = 0; half < 2; ++half) {
        const int t64 = half ? 31 - (int)blockIdx.x : (int)blockIdx.x;
        const int q0 = t64 * 64;
        const int row0 = q0 + w * 16;
        const int jtmax = t64;               // uniform across the block

        short8 aq0 = *(const short8*)(Qh + (size_t)(row0 + cl) * 64 + quad * 8);
        short8 aq1 = *(const short8*)(Qh + (size_t)(row0 + cl) * 64 + 32 + quad * 8);

        // ---- trip 1: row sums of exp(score) (max-free: |score| is O(1))
        float rsum[4] = {0.f, 0.f, 0.f, 0.f};
        __syncthreads();                     // prior half's LDS reads complete
        stageK(0, 0);
        {
            int cur = 0;
            for (int jt = 0; jt <= jtmax; ++jt, cur ^= 1) {
                __syncthreads();             // retires prefetch issued last phase
                if (jt < jtmax) stageK(jt + 1, cur ^ 1);
                const int j0 = jt * 64;
#pragma unroll
                for (int nt = 0; nt < 4; ++nt) {
                    const int r = nt * 16 + cl;
                    short8 k0 = *(const short8*)&Kt[cur][r][((quad) ^ (cl & 7)) * 8];
                    short8 k1 = *(const short8*)&Kt[cur][r][((quad + 4) ^ (cl & 7)) * 8];
                    f32x4 s = {0.f, 0.f, 0.f, 0.f};
                    s = __builtin_amdgcn_mfma_f32_16x16x32_bf16(aq0, k0, s, 0, 0, 0);
                    s = __builtin_amdgcn_mfma_f32_16x16x32_bf16(aq1, k1, s, 0, 0, 0);
                    const int jc = j0 + nt * 16 + cl;
#pragma unroll
                    for (int rg = 0; rg < 4; ++rg) {
                        int irow = row0 + quad * 4 + rg;
                        if (jc <= irow)
                            rsum[rg] += __expf(s[rg] * sc1 + mh * (float)(jc - irow));
                    }
                }
            }
        }
#pragma unroll
        for (int rg = 0; rg < 4; ++rg) {
            float v = rsum[rg];
            v += __shfl_xor(v, 1);
            v += __shfl_xor(v, 2);
            v += __shfl_xor(v, 4);
            v += __shfl_xor(v, 8);
            rsum[rg] = 1.0f / v;   // inv row-sum, valid on every lane of the quad
        }

        // ---- trip 2: recompute, normalize, emit attn, accumulate O = P @ V
        __syncthreads();           // all trip-1 reads done before restaging buf 0
        f32x4 oacc[4] = {};
        stageK(0, 0);
        stageV(0, 0);
        {
            int cur = 0;
            for (int jt = 0; jt <= jtmax; ++jt, cur ^= 1) {
                __syncthreads();             // retires prefetch issued last phase
                if (jt < jtmax) {
                    stageK(jt + 1, cur ^ 1);
                    stageV(jt * 64 + 64, cur ^ 1);
                }
                const int j0 = jt * 64;
                f32x4 sv[4];
#pragma unroll
                for (int nt = 0; nt < 4; ++nt) {
                    const int r = nt * 16 + cl;
                    short8 k0 = *(const short8*)&Kt[cur][r][((quad) ^ (cl & 7)) * 8];
                    short8 k1 = *(const short8*)&Kt[cur][r][((quad + 4) ^ (cl & 7)) * 8];
                    f32x4 s = {0.f, 0.f, 0.f, 0.f};
                    s = __builtin_amdgcn_mfma_f32_16x16x32_bf16(aq0, k0, s, 0, 0, 0);
                    sv[nt] = __builtin_amdgcn_mfma_f32_16x16x32_bf16(aq1, k1, s, 0, 0, 0);
                }
#pragma unroll
                for (int nt = 0; nt < 4; ++nt) {
                    const int jc = j0 + nt * 16 + cl;
#pragma unroll
                    for (int rg = 0; rg < 4; ++rg) {
                        const int irow = row0 + quad * 4 + rg;
                        float p = (jc <= irow)
                                      ? __expf(sv[nt][rg] * sc1 + mh * (float)(jc - irow)) * rsum[rg]
                                      : 0.f;
                        Ps[w][quad * 4 + rg]
                          [(((nt * 2 + (cl >> 3)) ^ ((quad * 4 + rg) & 7)) << 3) | (cl & 7)] =
                            f2bf(p);
                        __builtin_nontemporal_store(p, attnh + (size_t)irow * 2048 + jc);
                    }
                }

                short8 pa0 = *(const short8*)&Ps[w][cl][((quad ^ (cl & 7)) << 3)];
                short8 pa1 = *(const short8*)&Ps[w][cl][((((quad + 4)) ^ (cl & 7)) << 3)];

#pragma unroll
                for (int on = 0; on < 4; ++on) {
                    const int r = on * 16 + cl;
                    short8 v0 = *(const short8*)&Vt[cur][r][((quad) ^ (cl & 7)) * 8];
                    short8 v1 = *(const short8*)&Vt[cur][r][((quad + 4) ^ (cl & 7)) * 8];
                    oacc[on] = __builtin_amdgcn_mfma_f32_16x16x32_bf16(pa0, v0, oacc[on], 0, 0, 0);
                    oacc[on] = __builtin_amdgcn_mfma_f32_16x16x32_bf16(pa1, v1, oacc[on], 0, 0, 0);
                }
            }
        }

        // O epilogue: out[b, s, h*64 + d]
#pragma unroll
        for (int on = 0; on < 4; ++on) {
#pragma unroll
            for (int rg = 0; rg < 4; ++rg) {
                int srow2 = row0 + quad * 4 + rg;
                __builtin_nontemporal_store(
                    oacc[on][rg], out_ + ((size_t)b * 2048 + srow2) * 1024 + h * 64 + on * 16 + cl);
            }
        }

        // zero-fill strictly-future columns (d_out poisoned, zeros must be written)
        const int jz = (jtmax + 1) * 64;
        if (jz < 2048) {
            f32x4 z = {0.f, 0.f, 0.f, 0.f};
            for (int rr = 0; rr < 16; ++rr) {
                float* dst = attnh + (size_t)(row0 + rr) * 2048;
                for (int c = jz + lane * 4; c < 2048; c += 256)
                    __builtin_nontemporal_store(z, (f32x4*)(dst + c));
            }
        }
    }
}

// ---------------------------------------------------------------- launch
extern "C" void kernel_launch(void* const* d_in, const int* in_sizes, int n_in,
                              void* d_out, int out_size, void* d_ws, size_t ws_size,
                              hipStream_t stream) {
    const float* x = (const float*)d_in[0];     // [2,2048,1024]
    const float* Wk = (const float*)d_in[1];    // [1024,3072]
    float* out = (float*)d_out;                 // [2,2048,1024] fp32
    float* attn = out + (size_t)2 * 2048 * 1024;  // [2,16,2048,2048] fp32

    unsigned short* xb = (unsigned short*)d_ws;                 // 8 MB
    unsigned short* wtb = xb + (size_t)4096 * 1024;             // 6 MB
    unsigned short* qb = wtb + (size_t)3072 * 1024;             // 8 MB
    unsigned short* kb = qb + (size_t)32 * 2048 * 64;           // 8 MB
    unsigned short* vtb = kb + (size_t)32 * 2048 * 64;          // 8 MB

    cvt_x_kernel<<<dim3(4096), dim3(256), 0, stream>>>(x, xb, 4096 * 1024 / 4);
    cvt_wt_kernel<<<dim3(48, 16), dim3(256), 0, stream>>>(Wk, wtb);
    gemm_kqv_kernel<<<dim3(12, 16), dim3(512), 0, stream>>>(xb, wtb, qb, kb, vtb);
    attn_kernel<<<dim3(16, 16, 2), dim3(256), 0, stream>>>(qb, kb, vtb, out, attn);
}

// Round 7
// 678.800 us; speedup vs baseline: 1.2893x; 1.0120x over previous
//
#include <hip/hip_runtime.h>
#include <hip/hip_bf16.h>

typedef __attribute__((ext_vector_type(8))) short short8;
typedef __attribute__((ext_vector_type(4))) float f32x4;

// fp32 -> bf16 RNE
static __device__ __forceinline__ unsigned short f2bf(float f) {
    unsigned int x = __float_as_uint(f);
    x += 0x7fffu + ((x >> 16) & 1u);
    return (unsigned short)(x >> 16);
}

// async global->LDS, 16B per lane. LDS dest = wave-uniform base + lane*16.
static __device__ __forceinline__ void gld_lds16(const unsigned short* g, unsigned short* l) {
    __builtin_amdgcn_global_load_lds((const __attribute__((address_space(1))) void*)g,
                                     (__attribute__((address_space(3))) void*)l, 16, 0, 0);
}

// ---------------------------------------------------------------- converts
__global__ __launch_bounds__(256) void cvt_x_kernel(const float* __restrict__ in,
                                                    unsigned short* __restrict__ outb,
                                                    int n4) {
    int i = blockIdx.x * 256 + threadIdx.x;
    if (i < n4) {
        f32x4 v = *(const f32x4*)(in + (size_t)i * 4);
        ushort4 o;
        o.x = f2bf(v[0]); o.y = f2bf(v[1]); o.z = f2bf(v[2]); o.w = f2bf(v[3]);
        *(ushort4*)(outb + (size_t)i * 4) = o;
    }
}

// W [1024 x 3072] fp32  ->  WT [3072 x 1024] bf16   (tiled LDS transpose)
__global__ __launch_bounds__(256) void cvt_wt_kernel(const float* __restrict__ W,
                                                     unsigned short* __restrict__ WT) {
    __shared__ float t[64][65];
    const int n0 = blockIdx.x * 64;   // 48
    const int k0 = blockIdx.y * 64;   // 16
    const int tid = threadIdx.x;
#pragma unroll
    for (int i = 0; i < 16; ++i) {
        int lin = tid + i * 256;
        int rr = lin >> 6, cc = lin & 63;
        t[rr][cc] = W[(size_t)(k0 + rr) * 3072 + n0 + cc];
    }
    __syncthreads();
#pragma unroll
    for (int i = 0; i < 16; ++i) {
        int lin = tid + i * 256;
        int nn = lin >> 6, kk = lin & 63;
        WT[(size_t)(n0 + nn) * 1024 + k0 + kk] = f2bf(t[kk][nn]);
    }
}

// ---------------------------------------------------------------- GEMM (4-phase 256^2)
// C[4096,3072] = A[4096,1024] @ W[1024,3072], operands [rows,K] bf16.
// 256x256 tile, BK=64, 512 thr = 8 waves (2M x 4N), per-wave C = 128x64.
// LDS: 2 x (A 256x64 + B 256x64) bf16 = 128 KB, double-buffered.
// K-loop: 4 phases/tile; tile entry waits vmcnt(0) on loads issued a full
// tile earlier; raw s_barrier per phase (no vmcnt drain).
// Epilogue: BOTH v (transposed) and k/q (row-major) staged through the full
// 128 KB LDS as swizzled Cs tiles -> all global stores are 16B coalesced.
// (Old k/q path: 128 scalar 2B stores/wave = 32B segments + RMW.)
__global__ __launch_bounds__(512, 2) void gemm_kqv_kernel(
    const unsigned short* __restrict__ A,   // xb  [4096,1024]
    const unsigned short* __restrict__ BT,  // WTb [3072,1024]
    unsigned short* __restrict__ qb,
    unsigned short* __restrict__ kb,
    unsigned short* __restrict__ vtb) {
    __shared__ __attribute__((aligned(16))) unsigned short smem[2 * 2 * 256 * 64];  // 128 KB
    unsigned short (*As)[256][64] = (unsigned short(*)[256][64])smem;
    unsigned short (*Bs)[256][64] = (unsigned short(*)[256][64])(smem + 2 * 256 * 64);
    const int tid = threadIdx.x;
    const int w = tid >> 6, lane = tid & 63;
    const int quad = lane >> 4, cl = lane & 15;

    // XCD-aware bijective swizzle: 8 XCDs x 24 contiguous tiles (192 % 8 == 0).
    const int wg = (int)blockIdx.x + 12 * (int)blockIdx.y;   // 0..191
    const int wgs = (wg & 7) * 24 + (wg >> 3);
    const int m0 = (wgs / 12) * 256, n0 = (wgs % 12) * 256;
    const int wm = (w >> 2) * 128, wn = (w & 3) * 64;

    // staging: call i covers rows [i*64, i*64+64) (wave w does +w*8, 8 rows).
    // global chunk pre-swizzled: slot s of row r holds chunk s^(r&7).
    const int srow = lane >> 3;
    const int schk = (lane & 7) ^ srow;
    const unsigned short* Ap = A + (size_t)(m0 + w * 8 + srow) * 1024 + schk * 8;
    const unsigned short* Bp = BT + (size_t)(n0 + w * 8 + srow) * 1024 + schk * 8;

    f32x4 acc[8][4] = {};

    auto stageA = [&](int kk, int buf) {
#pragma unroll
        for (int i = 0; i < 4; ++i)
            gld_lds16(Ap + kk + (size_t)i * 64 * 1024, &As[buf][i * 64 + w * 8][0]);
    };
    auto stageB = [&](int kk, int buf) {
#pragma unroll
        for (int i = 0; i < 4; ++i)
            gld_lds16(Bp + kk + (size_t)i * 64 * 1024, &Bs[buf][i * 64 + w * 8][0]);
    };

    stageA(0, 0);
    stageB(0, 0);

    for (int kt = 0; kt < 16; ++kt) {
        const int cur = kt & 1;
        // tile kt's 8 loads were issued during kt-1 (>= 3 phases ago)
        asm volatile("s_waitcnt vmcnt(0)" ::: "memory");
        __builtin_amdgcn_s_barrier();

        // B fragments for the whole tile (live across the 4 phases)
        short8 bfr[4][2];
#pragma unroll
        for (int n = 0; n < 4; ++n)
#pragma unroll
            for (int kc = 0; kc < 2; ++kc)
                bfr[n][kc] = *(const short8*)
                    &Bs[cur][wn + n * 16 + cl][((kc * 4 + quad) ^ (cl & 7)) * 8];

#pragma unroll
        for (int q = 0; q < 4; ++q) {
            if (q == 0 && kt < 15) stageA(kt * 64 + 64, cur ^ 1);
            if (q == 1 && kt < 15) stageB(kt * 64 + 64, cur ^ 1);
            short8 af[2][2];
#pragma unroll
            for (int i = 0; i < 2; ++i)
#pragma unroll
                for (int kc = 0; kc < 2; ++kc)
                    af[i][kc] = *(const short8*)
                        &As[cur][wm + q * 32 + i * 16 + cl][((kc * 4 + quad) ^ (cl & 7)) * 8];
            __builtin_amdgcn_s_setprio(1);
#pragma unroll
            for (int i = 0; i < 2; ++i)
#pragma unroll
                for (int n = 0; n < 4; ++n)
#pragma unroll
                    for (int kc = 0; kc < 2; ++kc)
                        acc[q * 2 + i][n] = __builtin_amdgcn_mfma_f32_16x16x32_bf16(
                            af[i][kc], bfr[n][kc], acc[q * 2 + i][n], 0, 0, 0);
            __builtin_amdgcn_s_setprio(0);
            __builtin_amdgcn_sched_barrier(0);
            __builtin_amdgcn_s_barrier();   // raw: does NOT drain vmcnt
        }
    }

    // ---- epilogue (all LDS reads complete past the final barrier)
    const int chunk = n0 >> 10;           // 0:k 1:q 2:v (jnp.split order)
    const int d0 = n0 & 1023;
    const int b = m0 >> 11;               // 256-tile never crosses batch boundary
    const int s_base = m0 & 2047;

    if (chunk == 2) {
        // stage TRANSPOSED via LDS: Cs[d 0..255][s 0..255] (exactly 128 KB),
        // s-chunk XOR-swizzled by (d&7) -> bank-spread writes and reads.
        unsigned short (*Cs)[256] = (unsigned short(*)[256])smem;
        __syncthreads();                  // no DMA outstanding; safe full sync
#pragma unroll
        for (int im = 0; im < 8; ++im)
#pragma unroll
            for (int in = 0; in < 4; ++in)
#pragma unroll
                for (int rg = 0; rg < 4; ++rg) {
                    int dl = wn + in * 16 + cl;             // 0..255
                    int s = wm + im * 16 + quad * 4 + rg;   // 0..255
                    Cs[dl][(((s >> 3) ^ (dl & 7)) << 3) | (s & 7)] =
                        f2bf(acc[im][in][rg]);
                }
        __syncthreads();
#pragma unroll
        for (int it = 0; it < 16; ++it) {
            int l = it * 4096 + tid * 8;
            int dr = l >> 8;              // d-index 0..255
            int r = l & 255;              // s-offset (multiple of 8)
            int d = d0 + dr, hh = d >> 6, dd = d & 63;
            size_t dst = ((size_t)(b * 16 + hh) * 64 + dd) * 2048 + s_base + r;
            *(uint4*)(vtb + dst) = *(const uint4*)&Cs[dr][(((r >> 3) ^ (dr & 7)) << 3)];
        }
    } else {
        // k/q: stage ROW-MAJOR via LDS: Cs[s 0..255][d 0..255], d-chunk
        // XOR-swizzled by (s&7); then 16B coalesced stores (16 iters).
        unsigned short* outp = (chunk == 0) ? kb : qb;
        unsigned short (*Cs)[256] = (unsigned short(*)[256])smem;
        __syncthreads();
#pragma unroll
        for (int im = 0; im < 8; ++im)
#pragma unroll
            for (int in = 0; in < 4; ++in)
#pragma unroll
                for (int rg = 0; rg < 4; ++rg) {
                    int s = wm + im * 16 + quad * 4 + rg;   // 0..255
                    int d = wn + in * 16 + cl;              // 0..255
                    Cs[s][(((d >> 3) ^ (s & 7)) << 3) | (d & 7)] =
                        f2bf(acc[im][in][rg]);
                }
        __syncthreads();
#pragma unroll
        for (int it = 0; it < 16; ++it) {
            int l = it * 4096 + tid * 8;
            int sr = l >> 8;              // s-row 0..255
            int c = l & 255;              // d-offset (multiple of 8)
            int d = d0 + c, hh = d >> 6, dd = d & 63;
            size_t dst = ((size_t)(b * 16 + hh) * 2048 + s_base + sr) * 64 + dd;
            *(uint4*)(outp + dst) = *(const uint4*)&Cs[sr][(((c >> 3) ^ (sr & 7)) << 3)];
        }
    }
}

// ---------------------------------------------------------------- fused attention
// v6: KVBLK=128. grid (16, 16, 2), 4 waves, uniform-work pairing (bx then
// 31-bx). Each barrier step processes TWO 64-col subtiles from a 128-col
// double-buffered K/V stage -> barrier count halves (66 -> ~34 steps/block)
// and per-step fixed latency (ds_read lgkm, Ps round-trip, barrier sync)
// amortizes over 2x work. LDS = Kt 32K + Vt 32K + Ps 8K = 72 KB, 2 blocks/CU.
__global__ __launch_bounds__(256, 2) void attn_kernel(
    const unsigned short* __restrict__ qb,   // [B,H,S,64]
    const unsigned short* __restrict__ kb,   // [B,H,S,64]
    const unsigned short* __restrict__ vtb,  // [B,H,64,S]
    float* __restrict__ out_,                // [B,S,1024]
    float* __restrict__ attn) {              // [B,H,S,S]
    const int h = blockIdx.y;
    const int b = blockIdx.z;
    const int bh = b * 16 + h;
    const int tid = threadIdx.x;
    const int w = tid >> 6;
    const int lane = tid & 63;
    const int quad = lane >> 4;
    const int cl = lane & 15;

    const unsigned short* Qh = qb + (size_t)bh * 2048 * 64;
    const unsigned short* Kh = kb + (size_t)bh * 2048 * 64;
    const unsigned short* Vh = vtb + (size_t)bh * 64 * 2048;
    float* attnh = attn + (size_t)bh * 2048 * 2048;

    __shared__ __attribute__((aligned(16))) unsigned short Kt[2][2][64][64];  // 32 KB
    __shared__ __attribute__((aligned(16))) unsigned short Vt[2][2][64][64];  // 32 KB
    __shared__ __attribute__((aligned(16))) unsigned short Ps[4][16][64];     //  8 KB

    const int srow = lane >> 3;
    const int schk = (lane & 7) ^ srow;

    auto stageK = [&](int jt, int buf, int sub) {
#pragma unroll
        for (int i = 0; i < 2; ++i)
            gld_lds16(Kh + (size_t)(jt * 64 + w * 16 + i * 8 + srow) * 64 + schk * 8,
                      &Kt[buf][sub][w * 16 + i * 8][0]);
    };
    auto stageV = [&](int jt, int buf, int sub) {
#pragma unroll
        for (int i = 0; i < 2; ++i)
            gld_lds16(Vh + (size_t)(w * 16 + i * 8 + srow) * 2048 + jt * 64 + schk * 8,
                      &Vt[buf][sub][w * 16 + i * 8][0]);
    };

    const float mh = exp2f(-0.5f * (float)(h + 1));  // ALiBi slope 2^-((h+1)/2)
    const float sc1 = 1.0f / 32.0f;                  // 1/sqrt(1024)

    for (int half = 0; half < 2; ++half) {
        const int t64 = half ? 31 - (int)blockIdx.x : (int)blockIdx.x;
        const int q0 = t64 * 64;
        const int row0 = q0 + w * 16;
        const int jtmax = t64;               // uniform across the block
        const int N64 = jtmax + 1;
        const int NS = (N64 + 1) >> 1;       // 128-col steps

        short8 aq0 = *(const short8*)(Qh + (size_t)(row0 + cl) * 64 + quad * 8);
        short8 aq1 = *(const short8*)(Qh + (size_t)(row0 + cl) * 64 + 32 + quad * 8);

        // ---- trip 1: row sums of exp(score) (max-free: |score| is O(1))
        float rsum[4] = {0.f, 0.f, 0.f, 0.f};
        __syncthreads();                     // prior reads of LDS complete
        stageK(0, 0, 0);
        if (1 < N64) stageK(1, 0, 1);
        for (int s = 0; s < NS; ++s) {
            const int cur = s & 1;
            __syncthreads();                 // retires stage issued last step
            if (s + 1 < NS) {
                stageK(2 * s + 2, cur ^ 1, 0);
                if (2 * s + 3 < N64) stageK(2 * s + 3, cur ^ 1, 1);
            }
#pragma unroll
            for (int sub = 0; sub < 2; ++sub) {
                const int jt = 2 * s + sub;
                if (jt >= N64) continue;
                const int j0 = jt * 64;
#pragma unroll
                for (int nt = 0; nt < 4; ++nt) {
                    const int r = nt * 16 + cl;
                    short8 k0 = *(const short8*)&Kt[cur][sub][r][((quad) ^ (cl & 7)) * 8];
                    short8 k1 = *(const short8*)&Kt[cur][sub][r][((quad + 4) ^ (cl & 7)) * 8];
                    f32x4 sx = {0.f, 0.f, 0.f, 0.f};
                    sx = __builtin_amdgcn_mfma_f32_16x16x32_bf16(aq0, k0, sx, 0, 0, 0);
                    sx = __builtin_amdgcn_mfma_f32_16x16x32_bf16(aq1, k1, sx, 0, 0, 0);
                    const int jc = j0 + nt * 16 + cl;
#pragma unroll
                    for (int rg = 0; rg < 4; ++rg) {
                        int irow = row0 + quad * 4 + rg;
                        if (jc <= irow)
                            rsum[rg] += __expf(sx[rg] * sc1 + mh * (float)(jc - irow));
                    }
                }
            }
        }
#pragma unroll
        for (int rg = 0; rg < 4; ++rg) {
            float v = rsum[rg];
            v += __shfl_xor(v, 1);
            v += __shfl_xor(v, 2);
            v += __shfl_xor(v, 4);
            v += __shfl_xor(v, 8);
            rsum[rg] = 1.0f / v;   // inv row-sum, valid on every lane of the quad
        }

        // ---- trip 2: recompute, normalize, emit attn, accumulate O = P @ V
        __syncthreads();           // all trip-1 reads done before restaging buf 0
        f32x4 oacc[4] = {};
        stageK(0, 0, 0);
        stageV(0, 0, 0);
        if (1 < N64) { stageK(1, 0, 1); stageV(1, 0, 1); }
        for (int s = 0; s < NS; ++s) {
            const int cur = s & 1;
            __syncthreads();                 // retires stage issued last step
            if (s + 1 < NS) {
                stageK(2 * s + 2, cur ^ 1, 0);
                stageV(2 * s + 2, cur ^ 1, 0);
                if (2 * s + 3 < N64) {
                    stageK(2 * s + 3, cur ^ 1, 1);
                    stageV(2 * s + 3, cur ^ 1, 1);
                }
            }
#pragma unroll
            for (int sub = 0; sub < 2; ++sub) {
                const int jt = 2 * s + sub;
                if (jt >= N64) continue;
                const int j0 = jt * 64;
                f32x4 sv[4];
#pragma unroll
                for (int nt = 0; nt < 4; ++nt) {
                    const int r = nt * 16 + cl;
                    short8 k0 = *(const short8*)&Kt[cur][sub][r][((quad) ^ (cl & 7)) * 8];
                    short8 k1 = *(const short8*)&Kt[cur][sub][r][((quad + 4) ^ (cl & 7)) * 8];
                    f32x4 sx = {0.f, 0.f, 0.f, 0.f};
                    sx = __builtin_amdgcn_mfma_f32_16x16x32_bf16(aq0, k0, sx, 0, 0, 0);
                    sv[nt] = __builtin_amdgcn_mfma_f32_16x16x32_bf16(aq1, k1, sx, 0, 0, 0);
                }
#pragma unroll
                for (int nt = 0; nt < 4; ++nt) {
                    const int jc = j0 + nt * 16 + cl;
#pragma unroll
                    for (int rg = 0; rg < 4; ++rg) {
                        const int irow = row0 + quad * 4 + rg;
                        float p = (jc <= irow)
                                      ? __expf(sv[nt][rg] * sc1 + mh * (float)(jc - irow)) * rsum[rg]
                                      : 0.f;
                        Ps[w][quad * 4 + rg]
                          [(((nt * 2 + (cl >> 3)) ^ ((quad * 4 + rg) & 7)) << 3) | (cl & 7)] =
                            f2bf(p);
                        __builtin_nontemporal_store(p, attnh + (size_t)irow * 2048 + jc);
                    }
                }

                short8 pa0 = *(const short8*)&Ps[w][cl][((quad ^ (cl & 7)) << 3)];
                short8 pa1 = *(const short8*)&Ps[w][cl][((((quad + 4)) ^ (cl & 7)) << 3)];

#pragma unroll
                for (int on = 0; on < 4; ++on) {
                    const int r = on * 16 + cl;
                    short8 v0 = *(const short8*)&Vt[cur][sub][r][((quad) ^ (cl & 7)) * 8];
                    short8 v1 = *(const short8*)&Vt[cur][sub][r][((quad + 4) ^ (cl & 7)) * 8];
                    oacc[on] = __builtin_amdgcn_mfma_f32_16x16x32_bf16(pa0, v0, oacc[on], 0, 0, 0);
                    oacc[on] = __builtin_amdgcn_mfma_f32_16x16x32_bf16(pa1, v1, oacc[on], 0, 0, 0);
                }
            }
        }

        // O epilogue: out[b, s, h*64 + d]
#pragma unroll
        for (int on = 0; on < 4; ++on) {
#pragma unroll
            for (int rg = 0; rg < 4; ++rg) {
                int srow2 = row0 + quad * 4 + rg;
                __builtin_nontemporal_store(
                    oacc[on][rg], out_ + ((size_t)b * 2048 + srow2) * 1024 + h * 64 + on * 16 + cl);
            }
        }

        // zero-fill strictly-future columns (d_out poisoned, zeros must be written)
        const int jz = (jtmax + 1) * 64;
        if (jz < 2048) {
            f32x4 z = {0.f, 0.f, 0.f, 0.f};
            for (int rr = 0; rr < 16; ++rr) {
                float* dst = attnh + (size_t)(row0 + rr) * 2048;
                for (int c = jz + lane * 4; c < 2048; c += 256)
                    __builtin_nontemporal_store(z, (f32x4*)(dst + c));
            }
        }
    }
}

// ---------------------------------------------------------------- launch
extern "C" void kernel_launch(void* const* d_in, const int* in_sizes, int n_in,
                              void* d_out, int out_size, void* d_ws, size_t ws_size,
                              hipStream_t stream) {
    const float* x = (const float*)d_in[0];     // [2,2048,1024]
    const float* Wk = (const float*)d_in[1];    // [1024,3072]
    float* out = (float*)d_out;                 // [2,2048,1024] fp32
    float* attn = out + (size_t)2 * 2048 * 1024;  // [2,16,2048,2048] fp32

    unsigned short* xb = (unsigned short*)d_ws;                 // 8 MB
    unsigned short* wtb = xb + (size_t)4096 * 1024;             // 6 MB
    unsigned short* qb = wtb + (size_t)3072 * 1024;             // 8 MB
    unsigned short* kb = qb + (size_t)32 * 2048 * 64;           // 8 MB
    unsigned short* vtb = kb + (size_t)32 * 2048 * 64;          // 8 MB

    cvt_x_kernel<<<dim3(4096), dim3(256), 0, stream>>>(x, xb, 4096 * 1024 / 4);
    cvt_wt_kernel<<<dim3(48, 16), dim3(256), 0, stream>>>(Wk, wtb);
    gemm_kqv_kernel<<<dim3(12, 16), dim3(512), 0, stream>>>(xb, wtb, qb, kb, vtb);
    attn_kernel<<<dim3(16, 16, 2), dim3(256), 0, stream>>>(qb, kb, vtb, out, attn);
}